// Round 1
// baseline (1080.756 us; speedup 1.0000x reference)
//
#include <hip/hip_runtime.h>
#include <math.h>

#define DD 128
#define HH 4
#define CC 32

// ---------------- linear: y[r][o] = sum_k act(x[r][k]) * w[k][o] + b[o] -----
// 8 rows per block, 256 threads: sub = tid>>5 picks row, cg = tid&31 picks 4 cols.
__global__ __launch_bounds__(256) void k_linear(const float* __restrict__ x,
                                                const float* __restrict__ w,
                                                const float* __restrict__ b,
                                                float* __restrict__ y,
                                                int nrows, int apply_gelu) {
    __shared__ float xs[8][DD];
    int rbase = blockIdx.x * 8;
    // stage 8 input rows (with optional exact GELU)
    for (int i = threadIdx.x; i < 8 * DD; i += 256) {
        int r = rbase + (i >> 7);
        float v = (r < nrows) ? x[(size_t)r * DD + (i & 127)] : 0.f;
        if (apply_gelu) v = 0.5f * v * (1.f + erff(v * 0.70710678118654752f));
        xs[i >> 7][i & 127] = v;
    }
    __syncthreads();
    int sub = threadIdx.x >> 5;
    int cg  = threadIdx.x & 31;
    int r = rbase + sub;
    float4 acc = *(const float4*)&b[cg * 4];
    const float4* wv = (const float4*)w;  // [k][32] of float4
    #pragma unroll 4
    for (int k = 0; k < DD; ++k) {
        float xv = xs[sub][k];
        float4 wk = wv[k * 32 + cg];
        acc.x += xv * wk.x; acc.y += xv * wk.y;
        acc.z += xv * wk.z; acc.w += xv * wk.w;
    }
    if (r < nrows) *(float4*)&y[(size_t)r * DD + cg * 4] = acc;
}

// ---------------- out[n][f] = bias[f] --------------------------------------
__global__ void k_bias_init(float* __restrict__ out, const float* __restrict__ bias,
                            int n) {
    int gid = blockIdx.x * blockDim.x + threadIdx.x;
    if (gid < n * DD) out[gid] = bias[gid & 127];
}

// ---------------- per-edge attention logit + segment max --------------------
// thread = (edge, head). alpha_raw[e][h] = sum_c att[h][c]*lrelu(xl[d]+xl[s])
__global__ __launch_bounds__(256) void k_edge_alpha(const float* __restrict__ xl,
                                                    const int* __restrict__ src,
                                                    const int* __restrict__ dst,
                                                    const float* __restrict__ att,
                                                    float* __restrict__ alpha,
                                                    unsigned int* __restrict__ amax,
                                                    int nE) {
    __shared__ float att_l[DD];
    if (threadIdx.x < DD) att_l[threadIdx.x] = att[threadIdx.x];
    __syncthreads();
    int gid = blockIdx.x * 256 + threadIdx.x;
    int e = gid >> 2, h = gid & 3;
    if (e >= nE) return;
    int s = src[e], d = dst[e];
    const float4* xsv = (const float4*)&xl[(size_t)s * DD + h * CC];
    const float4* xdv = (const float4*)&xl[(size_t)d * DD + h * CC];
    const float4* av  = (const float4*)&att_l[h * CC];
    float acc = 0.f;
    #pragma unroll
    for (int q = 0; q < CC / 4; ++q) {
        float4 a = xsv[q], bq = xdv[q], t;
        t.x = a.x + bq.x; t.y = a.y + bq.y; t.z = a.z + bq.z; t.w = a.w + bq.w;
        t.x = t.x > 0.f ? t.x : 0.2f * t.x;
        t.y = t.y > 0.f ? t.y : 0.2f * t.y;
        t.z = t.z > 0.f ? t.z : 0.2f * t.z;
        t.w = t.w > 0.f ? t.w : 0.2f * t.w;
        float4 aa = av[q];
        acc += t.x * aa.x + t.y * aa.y + t.z * aa.z + t.w * aa.w;
    }
    alpha[(size_t)e * HH + h] = acc;
    unsigned int u = __float_as_uint(acc);
    u = (u & 0x80000000u) ? ~u : (u | 0x80000000u);   // order-preserving encode
    atomicMax(&amax[d * HH + h], u);
}

// ---------------- alpha = exp(raw - max); denom += alpha --------------------
__global__ __launch_bounds__(256) void k_edge_exp(const int* __restrict__ dst,
                                                  float* __restrict__ alpha,
                                                  const unsigned int* __restrict__ amax,
                                                  float* __restrict__ denom,
                                                  int nE) {
    int gid = blockIdx.x * 256 + threadIdx.x;
    int e = gid >> 2, h = gid & 3;
    if (e >= nE) return;
    int d = dst[e];
    unsigned int u = amax[d * HH + h];
    float m = (u & 0x80000000u) ? __uint_as_float(u ^ 0x80000000u)
                                : __uint_as_float(~u);
    float a = expf(alpha[(size_t)e * HH + h] - m);
    alpha[(size_t)e * HH + h] = a;
    atomicAdd(&denom[d * HH + h], a);
}

// ---------------- out[dst][f] += (alpha/denom) * xl[src][f] -----------------
__global__ __launch_bounds__(256) void k_scatter(const float* __restrict__ xl,
                                                 const int* __restrict__ src,
                                                 const int* __restrict__ dst,
                                                 const float* __restrict__ alpha,
                                                 const float* __restrict__ denom,
                                                 float* __restrict__ out,
                                                 int nE) {
    int gid = blockIdx.x * 256 + threadIdx.x;
    int e = gid >> 7, f = gid & 127;
    if (e >= nE) return;
    int s = src[e], d = dst[e];
    int h = f >> 5;
    float wgt = alpha[(size_t)e * HH + h] / denom[d * HH + h];
    atomicAdd(&out[(size_t)d * DD + f], wgt * xl[(size_t)s * DD + f]);
}

// ---------------- head: y = LN(x[:rows] @ w + b) * gamma + beta -------------
__global__ __launch_bounds__(128) void k_head(const float* __restrict__ x,
                                              const float* __restrict__ w,
                                              const float* __restrict__ b,
                                              const float* __restrict__ gamma,
                                              const float* __restrict__ beta,
                                              float* __restrict__ y) {
    int r = blockIdx.x, c = threadIdx.x;
    __shared__ float xr[DD];
    __shared__ float red[2];
    xr[c] = x[(size_t)r * DD + c];
    __syncthreads();
    float acc = b[c];
    #pragma unroll 4
    for (int k = 0; k < DD; ++k) acc += xr[k] * w[k * DD + c];
    // mean
    float s = acc;
    #pragma unroll
    for (int o = 32; o; o >>= 1) s += __shfl_down(s, o);
    if ((c & 63) == 0) red[c >> 6] = s;
    __syncthreads();
    float mean = (red[0] + red[1]) * (1.f / 128.f);
    __syncthreads();
    float dv = acc - mean;
    float s2 = dv * dv;
    #pragma unroll
    for (int o = 32; o; o >>= 1) s2 += __shfl_down(s2, o);
    if ((c & 63) == 0) red[c >> 6] = s2;
    __syncthreads();
    float var = (red[0] + red[1]) * (1.f / 128.f);
    y[(size_t)r * DD + c] = dv / sqrtf(var + 1e-12f) * gamma[c] + beta[c];
}

extern "C" void kernel_launch(void* const* d_in, const int* in_sizes, int n_in,
                              void* d_out, int out_size, void* d_ws, size_t ws_size,
                              hipStream_t stream) {
    const float* embs  = (const float*)d_in[0];
    const float* w0    = (const float*)d_in[1];
    const float* b0    = (const float*)d_in[2];
    const float* att0  = (const float*)d_in[3];
    const float* bias0 = (const float*)d_in[4];
    const float* w1    = (const float*)d_in[5];
    const float* b1    = (const float*)d_in[6];
    const float* att1  = (const float*)d_in[7];
    const float* bias1 = (const float*)d_in[8];
    const float* wout  = (const float*)d_in[9];
    const float* bout  = (const float*)d_in[10];
    const float* gamma = (const float*)d_in[11];
    const float* beta  = (const float*)d_in[12];
    const int* ei0 = (const int*)d_in[13];
    const int* ei1 = (const int*)d_in[14];

    int N  = in_sizes[0] / DD;
    int E0 = in_sizes[13] / 2;
    int E1 = in_sizes[14] / 2;
    int Emax = E0 > E1 ? E0 : E1;

    float* ws = (float*)d_ws;
    float* xl    = ws;                           // N*128
    float* out   = xl + (size_t)N * DD;          // N*128
    float* alpha = out + (size_t)N * DD;         // Emax*4
    unsigned int* amax = (unsigned int*)(alpha + (size_t)Emax * HH);  // N*4
    float* denom = (float*)(amax + (size_t)N * HH);                   // N*4

    int gLin   = (N + 7) / 8;
    int gInit  = (N * DD + 255) / 256;
    int gE4_0  = (E0 * HH + 255) / 256;
    int gE4_1  = (E1 * HH + 255) / 256;
    long long sc0 = ((long long)E0 * DD + 255) / 256;
    long long sc1 = ((long long)E1 * DD + 255) / 256;

    // ---------------- conv0 ----------------
    hipMemsetAsync(amax, 0, (size_t)N * HH * 2 * sizeof(float), stream);  // amax + denom
    k_linear<<<gLin, 256, 0, stream>>>(embs, w0, b0, xl, N, 0);
    k_bias_init<<<gInit, 256, 0, stream>>>(out, bias0, N);
    k_edge_alpha<<<gE4_0, 256, 0, stream>>>(xl, ei0, ei0 + E0, att0, alpha, amax, E0);
    k_edge_exp<<<gE4_0, 256, 0, stream>>>(ei0 + E0, alpha, amax, denom, E0);
    k_scatter<<<(int)sc0, 256, 0, stream>>>(xl, ei0, ei0 + E0, alpha, denom, out, E0);

    // ---------------- conv1 (gelu fused into linear input load) ----------------
    hipMemsetAsync(amax, 0, (size_t)N * HH * 2 * sizeof(float), stream);
    k_linear<<<gLin, 256, 0, stream>>>(out, w1, b1, xl, N, 1);
    k_bias_init<<<gInit, 256, 0, stream>>>(out, bias1, N);
    k_edge_alpha<<<gE4_1, 256, 0, stream>>>(xl, ei1, ei1 + E1, att1, alpha, amax, E1);
    k_edge_exp<<<gE4_1, 256, 0, stream>>>(ei1 + E1, alpha, amax, denom, E1);
    k_scatter<<<(int)sc1, 256, 0, stream>>>(xl, ei1, ei1 + E1, alpha, denom, out, E1);

    // ---------------- head ----------------
    k_head<<<1024, 128, 0, stream>>>(out, wout, bout, gamma, beta, (float*)d_out);
}

// Round 2
// 818.854 us; speedup vs baseline: 1.3198x; 1.3198x over previous
//
#include <hip/hip_runtime.h>
#include <math.h>

#define DD 128
#define HH 4
#define CC 32

// ---------------- linear: y[r][o] = sum_k act(x[r][k]) * w[k][o] + b[o] -----
__global__ __launch_bounds__(256) void k_linear(const float* __restrict__ x,
                                                const float* __restrict__ w,
                                                const float* __restrict__ b,
                                                float* __restrict__ y,
                                                int nrows, int apply_gelu) {
    __shared__ float xs[8][DD];
    int rbase = blockIdx.x * 8;
    for (int i = threadIdx.x; i < 8 * DD; i += 256) {
        int r = rbase + (i >> 7);
        float v = (r < nrows) ? x[(size_t)r * DD + (i & 127)] : 0.f;
        if (apply_gelu) v = 0.5f * v * (1.f + erff(v * 0.70710678118654752f));
        xs[i >> 7][i & 127] = v;
    }
    __syncthreads();
    int sub = threadIdx.x >> 5;
    int cg  = threadIdx.x & 31;
    int r = rbase + sub;
    float4 acc = *(const float4*)&b[cg * 4];
    const float4* wv = (const float4*)w;  // [k][32] of float4
    #pragma unroll 4
    for (int k = 0; k < DD; ++k) {
        float xv = xs[sub][k];
        float4 wk = wv[k * 32 + cg];
        acc.x += xv * wk.x; acc.y += xv * wk.y;
        acc.z += xv * wk.z; acc.w += xv * wk.w;
    }
    if (r < nrows) *(float4*)&y[(size_t)r * DD + cg * 4] = acc;
}

// ---------------- histogram of dst -----------------------------------------
__global__ __launch_bounds__(256) void k_hist(const int* __restrict__ dst,
                                              int* __restrict__ cnt, int nE) {
    int e = blockIdx.x * 256 + threadIdx.x;
    if (e < nE) atomicAdd(&cnt[dst[e]], 1);
}

// ---------------- 3-kernel exclusive scan over cnt[0..n) --------------------
__global__ __launch_bounds__(256) void k_scanA(const int* __restrict__ cnt,
                                               int* __restrict__ ex,
                                               int* __restrict__ bsum, int n) {
    __shared__ int s[256];
    int idx = blockIdx.x * 256 + threadIdx.x;
    int v = (idx < n) ? cnt[idx] : 0;
    s[threadIdx.x] = v;
    __syncthreads();
    for (int o = 1; o < 256; o <<= 1) {
        int t = (threadIdx.x >= o) ? s[threadIdx.x - o] : 0;
        __syncthreads();
        s[threadIdx.x] += t;
        __syncthreads();
    }
    if (idx < n) ex[idx] = s[threadIdx.x] - v;
    if (threadIdx.x == 255) bsum[blockIdx.x] = s[255];
}

__global__ __launch_bounds__(256) void k_scanB(int* __restrict__ bsum, int nb) {
    __shared__ int s[256];
    int v = (threadIdx.x < nb) ? bsum[threadIdx.x] : 0;
    s[threadIdx.x] = v;
    __syncthreads();
    for (int o = 1; o < 256; o <<= 1) {
        int t = (threadIdx.x >= o) ? s[threadIdx.x - o] : 0;
        __syncthreads();
        s[threadIdx.x] += t;
        __syncthreads();
    }
    if (threadIdx.x < nb) bsum[threadIdx.x] = s[threadIdx.x] - v;
}

__global__ __launch_bounds__(256) void k_scanC(const int* __restrict__ ex,
                                               const int* __restrict__ bsum,
                                               int* __restrict__ rowptr,
                                               int* __restrict__ cursor, int n) {
    int idx = blockIdx.x * 256 + threadIdx.x;
    if (idx < n) {
        int v = ex[idx] + bsum[blockIdx.x];
        rowptr[idx] = v;
        cursor[idx] = v;
    }
}

// ---------------- fused alpha + CSR fill ------------------------------------
// 4 threads per edge (one per head). Computes raw attention logit and drops
// {alpha[4], src} into the dst-node's bucket.
__global__ __launch_bounds__(256) void k_fill(const float* __restrict__ xl,
                                              const int* __restrict__ src,
                                              const int* __restrict__ dst,
                                              const float* __restrict__ att,
                                              int* __restrict__ cursor,
                                              float* __restrict__ salpha,
                                              int* __restrict__ ssrc, int nE) {
    __shared__ float att_l[DD];
    if (threadIdx.x < DD) att_l[threadIdx.x] = att[threadIdx.x];
    __syncthreads();
    int gid = blockIdx.x * 256 + threadIdx.x;
    int e = gid >> 2, h = gid & 3;
    if (e >= nE) return;
    int s = src[e], d = dst[e];
    const float4* xsv = (const float4*)&xl[(size_t)s * DD + h * CC];
    const float4* xdv = (const float4*)&xl[(size_t)d * DD + h * CC];
    const float4* av  = (const float4*)&att_l[h * CC];
    float acc = 0.f;
    #pragma unroll
    for (int q = 0; q < CC / 4; ++q) {
        float4 a = xsv[q], bq = xdv[q], t;
        t.x = a.x + bq.x; t.y = a.y + bq.y; t.z = a.z + bq.z; t.w = a.w + bq.w;
        t.x = t.x > 0.f ? t.x : 0.2f * t.x;
        t.y = t.y > 0.f ? t.y : 0.2f * t.y;
        t.z = t.z > 0.f ? t.z : 0.2f * t.z;
        t.w = t.w > 0.f ? t.w : 0.2f * t.w;
        float4 aa = av[q];
        acc += t.x * aa.x + t.y * aa.y + t.z * aa.z + t.w * aa.w;
    }
    int pos = 0;
    if (h == 0) pos = atomicAdd(&cursor[d], 1);
    pos = __shfl(pos, (threadIdx.x & 63) & ~3, 64);
    salpha[(size_t)pos * HH + h] = acc;
    if (h == 0) ssrc[pos] = s;
}

// ---------------- node-centric softmax + aggregate + bias -------------------
// 128 threads per node (2 nodes per 256-block). Thread f -> feature f, head f>>5.
__global__ __launch_bounds__(256) void k_agg(const float* __restrict__ xl,
                                             const int* __restrict__ rowptr,
                                             const int* __restrict__ cnt,
                                             const int* __restrict__ ssrc,
                                             const float* __restrict__ salpha,
                                             const float* __restrict__ bias,
                                             float* __restrict__ out, int n) {
    int node = blockIdx.x * 2 + (threadIdx.x >> 7);
    if (node >= n) return;
    int f = threadIdx.x & 127;
    int h = f >> 5;
    int rs = rowptr[node], deg = cnt[node];
    float mx = -3.4e38f;
    for (int k = 0; k < deg; ++k)
        mx = fmaxf(mx, salpha[(size_t)(rs + k) * HH + h]);
    float den = 0.f, acc = 0.f;
    for (int k = 0; k < deg; ++k) {
        float w = __expf(salpha[(size_t)(rs + k) * HH + h] - mx);
        den += w;
        acc += w * xl[(size_t)ssrc[rs + k] * DD + f];
    }
    float r = (deg > 0) ? acc / den : 0.f;
    out[(size_t)node * DD + f] = r + bias[f];
}

// ---------------- head: y = LN(x[:rows] @ w + b) * gamma + beta -------------
__global__ __launch_bounds__(128) void k_head(const float* __restrict__ x,
                                              const float* __restrict__ w,
                                              const float* __restrict__ b,
                                              const float* __restrict__ gamma,
                                              const float* __restrict__ beta,
                                              float* __restrict__ y) {
    int r = blockIdx.x, c = threadIdx.x;
    __shared__ float xr[DD];
    __shared__ float red[2];
    xr[c] = x[(size_t)r * DD + c];
    __syncthreads();
    float acc = b[c];
    #pragma unroll 4
    for (int k = 0; k < DD; ++k) acc += xr[k] * w[k * DD + c];
    float s = acc;
    #pragma unroll
    for (int o = 32; o; o >>= 1) s += __shfl_down(s, o);
    if ((c & 63) == 0) red[c >> 6] = s;
    __syncthreads();
    float mean = (red[0] + red[1]) * (1.f / 128.f);
    __syncthreads();
    float dv = acc - mean;
    float s2 = dv * dv;
    #pragma unroll
    for (int o = 32; o; o >>= 1) s2 += __shfl_down(s2, o);
    if ((c & 63) == 0) red[c >> 6] = s2;
    __syncthreads();
    float var = (red[0] + red[1]) * (1.f / 128.f);
    y[(size_t)r * DD + c] = dv / sqrtf(var + 1e-12f) * gamma[c] + beta[c];
}

extern "C" void kernel_launch(void* const* d_in, const int* in_sizes, int n_in,
                              void* d_out, int out_size, void* d_ws, size_t ws_size,
                              hipStream_t stream) {
    const float* embs  = (const float*)d_in[0];
    const float* w0    = (const float*)d_in[1];
    const float* b0    = (const float*)d_in[2];
    const float* att0  = (const float*)d_in[3];
    const float* bias0 = (const float*)d_in[4];
    const float* w1    = (const float*)d_in[5];
    const float* b1    = (const float*)d_in[6];
    const float* att1  = (const float*)d_in[7];
    const float* bias1 = (const float*)d_in[8];
    const float* wout  = (const float*)d_in[9];
    const float* bout  = (const float*)d_in[10];
    const float* gamma = (const float*)d_in[11];
    const float* beta  = (const float*)d_in[12];
    const int* ei0 = (const int*)d_in[13];
    const int* ei1 = (const int*)d_in[14];

    int N  = in_sizes[0] / DD;
    int E0 = in_sizes[13] / 2;
    int E1 = in_sizes[14] / 2;
    int Emax = E0 > E1 ? E0 : E1;

    // ---- workspace carve-up (floats) ----
    float* ws = (float*)d_ws;
    float* xl     = ws;                                   // N*128
    float* out    = xl + (size_t)N * DD;                  // N*128
    float* salpha = out + (size_t)N * DD;                 // Emax*4
    int*   ssrc   = (int*)(salpha + (size_t)Emax * HH);   // Emax
    int*   cnt    = ssrc + Emax;                          // N
    int*   rowptr = cnt + N;                              // N
    int*   cursor = rowptr + N;                           // N
    int*   ex     = cursor + N;                           // N
    int*   bsum   = ex + N;                               // 256

    int gLin  = (N + 7) / 8;
    int gScan = (N + 255) / 256;   // 196 blocks, fits k_scanB's 256-wide scan
    int gAgg  = (N + 1) / 2;

    for (int conv = 0; conv < 2; ++conv) {
        const int* ei   = conv ? ei1 : ei0;
        int nE          = conv ? E1 : E0;
        const float* w  = conv ? w1 : w0;
        const float* b  = conv ? b1 : b0;
        const float* at = conv ? att1 : att0;
        const float* bi = conv ? bias1 : bias0;
        const float* xin = conv ? out : embs;
        int gE  = (nE + 255) / 256;
        int gE4 = (nE * HH + 255) / 256;

        hipMemsetAsync(cnt, 0, (size_t)N * sizeof(int), stream);
        k_linear<<<gLin, 256, 0, stream>>>(xin, w, b, xl, N, conv /*gelu on conv1*/);
        k_hist<<<gE, 256, 0, stream>>>(ei + nE, cnt, nE);
        k_scanA<<<gScan, 256, 0, stream>>>(cnt, ex, bsum, N);
        k_scanB<<<1, 256, 0, stream>>>(bsum, gScan);
        k_scanC<<<gScan, 256, 0, stream>>>(ex, bsum, rowptr, cursor, N);
        k_fill<<<gE4, 256, 0, stream>>>(xl, ei, ei + nE, at, cursor, salpha, ssrc, nE);
        k_agg<<<gAgg, 256, 0, stream>>>(xl, rowptr, cnt, ssrc, salpha, bi, out, N);
    }

    k_head<<<1024, 128, 0, stream>>>(out, wout, bout, gamma, beta, (float*)d_out);
}

// Round 3
// 659.092 us; speedup vs baseline: 1.6398x; 1.2424x over previous
//
#include <hip/hip_runtime.h>
#include <math.h>

#define DD 128
#define HH 4
#define CC 32

// ---------------- linear: y[r][o] = sum_k act(x[r][k]) * w[k][o] + b[o] -----
__global__ __launch_bounds__(256) void k_linear(const float* __restrict__ x,
                                                const float* __restrict__ w,
                                                const float* __restrict__ b,
                                                float* __restrict__ y,
                                                int nrows, int apply_gelu) {
    __shared__ float xs[8][DD];
    int rbase = blockIdx.x * 8;
    for (int i = threadIdx.x; i < 8 * DD; i += 256) {
        int r = rbase + (i >> 7);
        float v = (r < nrows) ? x[(size_t)r * DD + (i & 127)] : 0.f;
        if (apply_gelu) v = 0.5f * v * (1.f + erff(v * 0.70710678118654752f));
        xs[i >> 7][i & 127] = v;
    }
    __syncthreads();
    int sub = threadIdx.x >> 5;
    int cg  = threadIdx.x & 31;
    int r = rbase + sub;
    float4 acc = *(const float4*)&b[cg * 4];
    const float4* wv = (const float4*)w;  // [k][32] of float4
    #pragma unroll 4
    for (int k = 0; k < DD; ++k) {
        float xv = xs[sub][k];
        float4 wk = wv[k * 32 + cg];
        acc.x += xv * wk.x; acc.y += xv * wk.y;
        acc.z += xv * wk.z; acc.w += xv * wk.w;
    }
    if (r < nrows) *(float4*)&y[(size_t)r * DD + cg * 4] = acc;
}

// ---------------- histogram of dst -----------------------------------------
__global__ __launch_bounds__(256) void k_hist(const int* __restrict__ dst,
                                              int* __restrict__ cnt, int nE) {
    int e = blockIdx.x * 256 + threadIdx.x;
    if (e < nE) atomicAdd(&cnt[dst[e]], 1);
}

// ---------------- 3-kernel exclusive scan over cnt[0..n) --------------------
__global__ __launch_bounds__(256) void k_scanA(const int* __restrict__ cnt,
                                               int* __restrict__ ex,
                                               int* __restrict__ bsum, int n) {
    __shared__ int s[256];
    int idx = blockIdx.x * 256 + threadIdx.x;
    int v = (idx < n) ? cnt[idx] : 0;
    s[threadIdx.x] = v;
    __syncthreads();
    for (int o = 1; o < 256; o <<= 1) {
        int t = (threadIdx.x >= o) ? s[threadIdx.x - o] : 0;
        __syncthreads();
        s[threadIdx.x] += t;
        __syncthreads();
    }
    if (idx < n) ex[idx] = s[threadIdx.x] - v;
    if (threadIdx.x == 255) bsum[blockIdx.x] = s[255];
}

__global__ __launch_bounds__(256) void k_scanB(int* __restrict__ bsum, int nb) {
    __shared__ int s[256];
    int v = (threadIdx.x < nb) ? bsum[threadIdx.x] : 0;
    s[threadIdx.x] = v;
    __syncthreads();
    for (int o = 1; o < 256; o <<= 1) {
        int t = (threadIdx.x >= o) ? s[threadIdx.x - o] : 0;
        __syncthreads();
        s[threadIdx.x] += t;
        __syncthreads();
    }
    if (threadIdx.x < nb) bsum[threadIdx.x] = s[threadIdx.x] - v;
}

__global__ __launch_bounds__(256) void k_scanC(const int* __restrict__ ex,
                                               const int* __restrict__ bsum,
                                               int* __restrict__ rowptr,
                                               int* __restrict__ cursor, int n) {
    int idx = blockIdx.x * 256 + threadIdx.x;
    if (idx < n) {
        int v = ex[idx] + bsum[blockIdx.x];
        rowptr[idx] = v;
        cursor[idx] = v;
    }
}

// ---------------- CSR fill: bucket src ids by dst ---------------------------
__global__ __launch_bounds__(256) void k_fill_idx(const int* __restrict__ src,
                                                  const int* __restrict__ dst,
                                                  int* __restrict__ cursor,
                                                  int* __restrict__ ssrc, int nE) {
    int e = blockIdx.x * 256 + threadIdx.x;
    if (e < nE) {
        int pos = atomicAdd(&cursor[dst[e]], 1);
        ssrc[pos] = src[e];
    }
}

// ---------------- fused logit + online-softmax + aggregate + bias -----------
// 128 threads per node (2 nodes / 256-block). Thread f -> feature f, head f>>5.
// Logit for edge (s->d): sum_c att[h][c]*lrelu(xd[c]+xs[c]) via 32-lane shfl
// reduce; online softmax keeps one pass over the node's edge bucket.
__global__ __launch_bounds__(256) void k_agg(const float* __restrict__ xl,
                                             const int* __restrict__ rowptr,
                                             const int* __restrict__ cnt,
                                             const int* __restrict__ ssrc,
                                             const float* __restrict__ att,
                                             const float* __restrict__ bias,
                                             float* __restrict__ out, int n) {
    int node = blockIdx.x * 2 + (threadIdx.x >> 7);
    if (node >= n) return;
    int f = threadIdx.x & 127;
    float attf = att[f];
    int rs = rowptr[node], deg = cnt[node];
    float xd = xl[(size_t)node * DD + f];

    float m = -3.4e38f, den = 0.f, acc = 0.f;
    int   s0 = 0, s1 = 0;
    float v0 = 0.f, v1 = 0.f;
    if (deg > 0) { s0 = ssrc[rs];     v0 = xl[(size_t)s0 * DD + f]; }
    if (deg > 1) { s1 = ssrc[rs + 1]; v1 = xl[(size_t)s1 * DD + f]; }

    for (int k = 0; k < deg; ++k) {
        int s2 = 0; float v2 = 0.f;
        if (k + 2 < deg) { s2 = ssrc[rs + k + 2]; v2 = xl[(size_t)s2 * DD + f]; }
        float t = xd + v0;
        t = t > 0.f ? t : 0.2f * t;
        float l = t * attf;
        #pragma unroll
        for (int o = 16; o; o >>= 1) l += __shfl_xor(l, o, 64);  // within 32-lane head
        float mn = fmaxf(m, l);
        float corr = __expf(m - mn);     // first iter: underflows to 0, correct
        float w    = __expf(l - mn);
        den = den * corr + w;
        acc = acc * corr + w * v0;
        m = mn;
        s0 = s1; v0 = v1; s1 = s2; v1 = v2;
    }
    float r = (deg > 0) ? acc / den : 0.f;
    out[(size_t)node * DD + f] = r + bias[f];
}

// ---------------- head: y = LN(x[:rows] @ w + b) * gamma + beta -------------
__global__ __launch_bounds__(128) void k_head(const float* __restrict__ x,
                                              const float* __restrict__ w,
                                              const float* __restrict__ b,
                                              const float* __restrict__ gamma,
                                              const float* __restrict__ beta,
                                              float* __restrict__ y) {
    int r = blockIdx.x, c = threadIdx.x;
    __shared__ float xr[DD];
    __shared__ float red[2];
    xr[c] = x[(size_t)r * DD + c];
    __syncthreads();
    float acc = b[c];
    #pragma unroll 4
    for (int k = 0; k < DD; ++k) acc += xr[k] * w[k * DD + c];
    float s = acc;
    #pragma unroll
    for (int o = 32; o; o >>= 1) s += __shfl_down(s, o);
    if ((c & 63) == 0) red[c >> 6] = s;
    __syncthreads();
    float mean = (red[0] + red[1]) * (1.f / 128.f);
    __syncthreads();
    float dv = acc - mean;
    float s2 = dv * dv;
    #pragma unroll
    for (int o = 32; o; o >>= 1) s2 += __shfl_down(s2, o);
    if ((c & 63) == 0) red[c >> 6] = s2;
    __syncthreads();
    float var = (red[0] + red[1]) * (1.f / 128.f);
    y[(size_t)r * DD + c] = dv / sqrtf(var + 1e-12f) * gamma[c] + beta[c];
}

extern "C" void kernel_launch(void* const* d_in, const int* in_sizes, int n_in,
                              void* d_out, int out_size, void* d_ws, size_t ws_size,
                              hipStream_t stream) {
    const float* embs  = (const float*)d_in[0];
    const float* w0    = (const float*)d_in[1];
    const float* b0    = (const float*)d_in[2];
    const float* att0  = (const float*)d_in[3];
    const float* bias0 = (const float*)d_in[4];
    const float* w1    = (const float*)d_in[5];
    const float* b1    = (const float*)d_in[6];
    const float* att1  = (const float*)d_in[7];
    const float* bias1 = (const float*)d_in[8];
    const float* wout  = (const float*)d_in[9];
    const float* bout  = (const float*)d_in[10];
    const float* gamma = (const float*)d_in[11];
    const float* beta  = (const float*)d_in[12];
    const int* ei0 = (const int*)d_in[13];
    const int* ei1 = (const int*)d_in[14];

    int N  = in_sizes[0] / DD;
    int E0 = in_sizes[13] / 2;
    int E1 = in_sizes[14] / 2;
    int Emax = E0 > E1 ? E0 : E1;

    // ---- workspace carve-up ----
    float* ws = (float*)d_ws;
    float* xl     = ws;                                   // N*128
    float* out    = xl + (size_t)N * DD;                  // N*128
    int*   ssrc   = (int*)(out + (size_t)N * DD);         // Emax
    int*   cnt    = ssrc + Emax;                          // N
    int*   rowptr = cnt + N;                              // N
    int*   cursor = rowptr + N;                           // N
    int*   ex     = cursor + N;                           // N
    int*   bsum   = ex + N;                               // 256

    int gLin  = (N + 7) / 8;
    int gScan = (N + 255) / 256;   // 196 blocks, fits k_scanB's 256-wide scan
    int gAgg  = (N + 1) / 2;

    for (int conv = 0; conv < 2; ++conv) {
        const int* ei   = conv ? ei1 : ei0;
        int nE          = conv ? E1 : E0;
        const float* w  = conv ? w1 : w0;
        const float* b  = conv ? b1 : b0;
        const float* at = conv ? att1 : att0;
        const float* bi = conv ? bias1 : bias0;
        const float* xin = conv ? out : embs;
        int gE = (nE + 255) / 256;

        hipMemsetAsync(cnt, 0, (size_t)N * sizeof(int), stream);
        k_linear<<<gLin, 256, 0, stream>>>(xin, w, b, xl, N, conv /*gelu on conv1*/);
        k_hist<<<gE, 256, 0, stream>>>(ei + nE, cnt, nE);
        k_scanA<<<gScan, 256, 0, stream>>>(cnt, ex, bsum, N);
        k_scanB<<<1, 256, 0, stream>>>(bsum, gScan);
        k_scanC<<<gScan, 256, 0, stream>>>(ex, bsum, rowptr, cursor, N);
        k_fill_idx<<<gE, 256, 0, stream>>>(ei, ei + nE, cursor, ssrc, nE);
        k_agg<<<gAgg, 256, 0, stream>>>(xl, rowptr, cnt, ssrc, at, bi, out, N);
    }

    k_head<<<1024, 128, 0, stream>>>(out, wout, bout, gamma, beta, (float*)d_out);
}

// Round 4
// 465.614 us; speedup vs baseline: 2.3211x; 1.4155x over previous
//
#include <hip/hip_runtime.h>
#include <math.h>

#define DD 128
#define HH 4
#define CC 32

// ---------------- linear: y[r][o] = sum_k act(x[r][k]) * w[k][o] + b[o] -----
__global__ __launch_bounds__(256) void k_linear(const float* __restrict__ x,
                                                const float* __restrict__ w,
                                                const float* __restrict__ b,
                                                float* __restrict__ y,
                                                int nrows, int apply_gelu) {
    __shared__ float xs[8][DD];
    int rbase = blockIdx.x * 8;
    for (int i = threadIdx.x; i < 8 * DD; i += 256) {
        int r = rbase + (i >> 7);
        float v = (r < nrows) ? x[(size_t)r * DD + (i & 127)] : 0.f;
        if (apply_gelu) v = 0.5f * v * (1.f + erff(v * 0.70710678118654752f));
        xs[i >> 7][i & 127] = v;
    }
    __syncthreads();
    int sub = threadIdx.x >> 5;
    int cg  = threadIdx.x & 31;
    int r = rbase + sub;
    float4 acc = *(const float4*)&b[cg * 4];
    const float4* wv = (const float4*)w;  // [k][32] of float4
    #pragma unroll 4
    for (int k = 0; k < DD; ++k) {
        float xv = xs[sub][k];
        float4 wk = wv[k * 32 + cg];
        acc.x += xv * wk.x; acc.y += xv * wk.y;
        acc.z += xv * wk.z; acc.w += xv * wk.w;
    }
    if (r < nrows) *(float4*)&y[(size_t)r * DD + cg * 4] = acc;
}

// ---------------- histogram of dst for BOTH convs ---------------------------
__global__ __launch_bounds__(256) void k_hist2(const int* __restrict__ dst0, int E0p,
                                               const int* __restrict__ dst1, int E1p,
                                               int* __restrict__ cnt, int N) {
    int e = blockIdx.x * 256 + threadIdx.x;
    if (e < E0p) atomicAdd(&cnt[dst0[e]], 1);
    else if (e - E0p < E1p) atomicAdd(&cnt[N + dst1[e - E0p]], 1);
}

// ---------------- 3-kernel exclusive scan over cnt[0..n) --------------------
__global__ __launch_bounds__(256) void k_scanA(const int* __restrict__ cnt,
                                               int* __restrict__ ex,
                                               int* __restrict__ bsum, int n) {
    __shared__ int s[256];
    int idx = blockIdx.x * 256 + threadIdx.x;
    int v = (idx < n) ? cnt[idx] : 0;
    s[threadIdx.x] = v;
    __syncthreads();
    for (int o = 1; o < 256; o <<= 1) {
        int t = (threadIdx.x >= o) ? s[threadIdx.x - o] : 0;
        __syncthreads();
        s[threadIdx.x] += t;
        __syncthreads();
    }
    if (idx < n) ex[idx] = s[threadIdx.x] - v;
    if (threadIdx.x == 255) bsum[blockIdx.x] = s[255];
}

__global__ __launch_bounds__(512) void k_scanB(int* __restrict__ bsum, int nb) {
    __shared__ int s[512];
    int v = (threadIdx.x < nb) ? bsum[threadIdx.x] : 0;
    s[threadIdx.x] = v;
    __syncthreads();
    for (int o = 1; o < 512; o <<= 1) {
        int t = (threadIdx.x >= o) ? s[threadIdx.x - o] : 0;
        __syncthreads();
        s[threadIdx.x] += t;
        __syncthreads();
    }
    if (threadIdx.x < nb) bsum[threadIdx.x] = s[threadIdx.x] - v;
}

__global__ __launch_bounds__(256) void k_scanC(const int* __restrict__ ex,
                                               const int* __restrict__ bsum,
                                               int* __restrict__ rowptr,
                                               int* __restrict__ cursor, int n) {
    int idx = blockIdx.x * 256 + threadIdx.x;
    if (idx < n) {
        int v = ex[idx] + bsum[blockIdx.x];
        rowptr[idx] = v;
        cursor[idx] = v;
    }
}

// ---------------- CSR fill for BOTH convs -----------------------------------
__global__ __launch_bounds__(256) void k_fill2(const int* __restrict__ src0,
                                               const int* __restrict__ dst0, int E0p,
                                               const int* __restrict__ src1,
                                               const int* __restrict__ dst1, int E1p,
                                               int* __restrict__ cursor,
                                               int* __restrict__ ssrc, int N) {
    int e = blockIdx.x * 256 + threadIdx.x;
    if (e < E0p) {
        int pos = atomicAdd(&cursor[dst0[e]], 1);
        ssrc[pos] = src0[e];
    } else if (e - E0p < E1p) {
        int pos = atomicAdd(&cursor[N + dst1[e - E0p]], 1);
        ssrc[pos] = src1[e - E0p];
    }
}

// ---------------- fused logit + online-softmax + aggregate + bias -----------
// ONE WAVE per node; lane holds features {2*lane, 2*lane+1} (same head).
// Logit reduce: 4-step shfl_xor over each 16-lane head group. 2-edge unroll:
// two independent logit chains + 3 exps / 2 edges.
__global__ __launch_bounds__(256) void k_agg(const float* __restrict__ xl,
                                             const int* __restrict__ rowptr,
                                             const int* __restrict__ cnt,
                                             const int* __restrict__ ssrc,
                                             const float* __restrict__ att,
                                             const float* __restrict__ bias,
                                             float* __restrict__ out, int n) {
    int node = __builtin_amdgcn_readfirstlane(blockIdx.x * 4 + (threadIdx.x >> 6));
    if (node >= n) return;
    int lane = threadIdx.x & 63;
    float2 attv = *(const float2*)&att[lane * 2];
    float2 xd   = *(const float2*)&xl[(size_t)node * DD + lane * 2];
    int rs  = rowptr[node];
    int deg = cnt[node];

    float m = -3.4e38f, den = 0.f;
    float accx = 0.f, accy = 0.f;
    int sA = (deg > 0) ? ssrc[rs] : 0;
    int sB = (deg > 1) ? ssrc[rs + 1] : 0;
    float2 vA = *(const float2*)&xl[(size_t)sA * DD + lane * 2];
    float2 vB = *(const float2*)&xl[(size_t)sB * DD + lane * 2];

    int k = 0;
    for (; k + 1 < deg; k += 2) {
        int sC = (k + 2 < deg) ? ssrc[rs + k + 2] : 0;
        int sD = (k + 3 < deg) ? ssrc[rs + k + 3] : 0;
        float2 vC = *(const float2*)&xl[(size_t)sC * DD + lane * 2];
        float2 vD = *(const float2*)&xl[(size_t)sD * DD + lane * 2];

        float tx = xd.x + vA.x, ty = xd.y + vA.y;
        tx = tx > 0.f ? tx : 0.2f * tx;
        ty = ty > 0.f ? ty : 0.2f * ty;
        float l0 = tx * attv.x + ty * attv.y;
        tx = xd.x + vB.x; ty = xd.y + vB.y;
        tx = tx > 0.f ? tx : 0.2f * tx;
        ty = ty > 0.f ? ty : 0.2f * ty;
        float l1 = tx * attv.x + ty * attv.y;
        #pragma unroll
        for (int o = 8; o; o >>= 1) {
            l0 += __shfl_xor(l0, o, 64);
            l1 += __shfl_xor(l1, o, 64);
        }
        float mn = fmaxf(fmaxf(m, l0), l1);   // v_max3
        float corr = __expf(m - mn);          // first iter: exp(-inf)=0
        float w0 = __expf(l0 - mn);
        float w1 = __expf(l1 - mn);
        den  = den  * corr + w0 + w1;
        accx = accx * corr + w0 * vA.x + w1 * vB.x;
        accy = accy * corr + w0 * vA.y + w1 * vB.y;
        m = mn;
        sA = sC; sB = sD; vA = vC; vB = vD;
    }
    if (k < deg) {  // odd tail: edge k is in vA
        float tx = xd.x + vA.x, ty = xd.y + vA.y;
        tx = tx > 0.f ? tx : 0.2f * tx;
        ty = ty > 0.f ? ty : 0.2f * ty;
        float l0 = tx * attv.x + ty * attv.y;
        #pragma unroll
        for (int o = 8; o; o >>= 1) l0 += __shfl_xor(l0, o, 64);
        float mn = fmaxf(m, l0);
        float corr = __expf(m - mn);
        float w0 = __expf(l0 - mn);
        den  = den  * corr + w0;
        accx = accx * corr + w0 * vA.x;
        accy = accy * corr + w0 * vA.y;
    }

    float inv = (deg > 0) ? 1.f / den : 0.f;
    float2 o2;
    o2.x = accx * inv + bias[lane * 2];
    o2.y = accy * inv + bias[lane * 2 + 1];
    *(float2*)&out[(size_t)node * DD + lane * 2] = o2;
}

// ---------------- head: y = LN(x[:rows] @ w + b) * gamma + beta -------------
__global__ __launch_bounds__(128) void k_head(const float* __restrict__ x,
                                              const float* __restrict__ w,
                                              const float* __restrict__ b,
                                              const float* __restrict__ gamma,
                                              const float* __restrict__ beta,
                                              float* __restrict__ y) {
    int r = blockIdx.x, c = threadIdx.x;
    __shared__ float xr[DD];
    __shared__ float red[2];
    xr[c] = x[(size_t)r * DD + c];
    __syncthreads();
    float acc = b[c];
    #pragma unroll 4
    for (int k = 0; k < DD; ++k) acc += xr[k] * w[k * DD + c];
    float s = acc;
    #pragma unroll
    for (int o = 32; o; o >>= 1) s += __shfl_down(s, o);
    if ((c & 63) == 0) red[c >> 6] = s;
    __syncthreads();
    float mean = (red[0] + red[1]) * (1.f / 128.f);
    __syncthreads();
    float dv = acc - mean;
    float s2 = dv * dv;
    #pragma unroll
    for (int o = 32; o; o >>= 1) s2 += __shfl_down(s2, o);
    if ((c & 63) == 0) red[c >> 6] = s2;
    __syncthreads();
    float var = (red[0] + red[1]) * (1.f / 128.f);
    y[(size_t)r * DD + c] = dv / sqrtf(var + 1e-12f) * gamma[c] + beta[c];
}

extern "C" void kernel_launch(void* const* d_in, const int* in_sizes, int n_in,
                              void* d_out, int out_size, void* d_ws, size_t ws_size,
                              hipStream_t stream) {
    const float* embs  = (const float*)d_in[0];
    const float* w0    = (const float*)d_in[1];
    const float* b0    = (const float*)d_in[2];
    const float* att0  = (const float*)d_in[3];
    const float* bias0 = (const float*)d_in[4];
    const float* w1    = (const float*)d_in[5];
    const float* b1    = (const float*)d_in[6];
    const float* att1  = (const float*)d_in[7];
    const float* bias1 = (const float*)d_in[8];
    const float* wout  = (const float*)d_in[9];
    const float* bout  = (const float*)d_in[10];
    const float* gamma = (const float*)d_in[11];
    const float* beta  = (const float*)d_in[12];
    const int* ei0 = (const int*)d_in[13];
    const int* ei1 = (const int*)d_in[14];

    int N  = in_sizes[0] / DD;
    int E0 = in_sizes[13] / 2;
    int E1 = in_sizes[14] / 2;
    int N2 = 2 * N;

    // ---- workspace carve-up ----
    float* ws = (float*)d_ws;
    float* xl     = ws;                                   // N*128
    float* out    = xl + (size_t)N * DD;                  // N*128
    int*   ssrc   = (int*)(out + (size_t)N * DD);         // E0+E1
    int*   cnt    = ssrc + (E0 + E1);                     // 2N
    int*   rowptr = cnt + N2;                             // 2N
    int*   cursor = rowptr + N2;                          // 2N
    int*   ex     = cursor + N2;                          // 2N
    int*   bsum   = ex + N2;                              // 512

    int gLin   = (N + 7) / 8;
    int gScan  = (N2 + 255) / 256;          // 391 blocks <= 512-wide scanB
    int gAgg   = (N + 3) / 4;
    int gEdges = (E0 + E1 + 255) / 256;

    // ---- build CSR for both convs up front ----
    hipMemsetAsync(cnt, 0, (size_t)N2 * sizeof(int), stream);
    k_hist2<<<gEdges, 256, 0, stream>>>(ei0 + E0, E0, ei1 + E1, E1, cnt, N);
    k_scanA<<<gScan, 256, 0, stream>>>(cnt, ex, bsum, N2);
    k_scanB<<<1, 512, 0, stream>>>(bsum, gScan);
    k_scanC<<<gScan, 256, 0, stream>>>(ex, bsum, rowptr, cursor, N2);
    k_fill2<<<gEdges, 256, 0, stream>>>(ei0, ei0 + E0, E0, ei1, ei1 + E1, E1,
                                        cursor, ssrc, N);

    // ---- conv0 ----
    k_linear<<<gLin, 256, 0, stream>>>(embs, w0, b0, xl, N, 0);
    k_agg<<<gAgg, 256, 0, stream>>>(xl, rowptr, cnt, ssrc, att0, bias0, out, N);

    // ---- conv1 (gelu fused into linear input load) ----
    k_linear<<<gLin, 256, 0, stream>>>(out, w1, b1, xl, N, 1);
    k_agg<<<gAgg, 256, 0, stream>>>(xl, rowptr + N, cnt + N, ssrc, att1, bias1,
                                    out, N);

    // ---- head ----
    k_head<<<1024, 128, 0, stream>>>(out, wout, bout, gamma, beta, (float*)d_out);
}

// Round 5
// 269.803 us; speedup vs baseline: 4.0057x; 1.7258x over previous
//
#include <hip/hip_runtime.h>
#include <math.h>

#define DD 128
#define HH 4
#define CC 32

// ---------------- linear: y[r][o] = sum_k act(x[r][k]) * w[k][o] + b[o] -----
// 64 rows/block, 256 threads = 8 groups x 32 lanes. Group g computes rows
// g*8..g*8+7; lane cg computes cols 4cg..4cg+3. w staged in LDS 32-k chunks:
// one LDS float4 read feeds 32 FMAs.
__global__ __launch_bounds__(256) void k_linear(const float* __restrict__ x,
                                                const float* __restrict__ w,
                                                const float* __restrict__ b,
                                                float* __restrict__ y,
                                                int nrows, int apply_gelu) {
    __shared__ float  xs[64][DD];     // 32 KB
    __shared__ float4 wb[32][32];     // 16 KB  [kk][cg]
    int rbase = blockIdx.x * 64;

    // stage 64 rows as float4 (optional exact GELU)
    for (int i = threadIdx.x; i < 64 * 32; i += 256) {
        int r = rbase + (i >> 5);
        float4 v = make_float4(0.f, 0.f, 0.f, 0.f);
        if (r < nrows) v = ((const float4*)x)[(size_t)r * 32 + (i & 31)];
        if (apply_gelu) {
            v.x = 0.5f * v.x * (1.f + erff(v.x * 0.70710678f));
            v.y = 0.5f * v.y * (1.f + erff(v.y * 0.70710678f));
            v.z = 0.5f * v.z * (1.f + erff(v.z * 0.70710678f));
            v.w = 0.5f * v.w * (1.f + erff(v.w * 0.70710678f));
        }
        *(float4*)&xs[i >> 5][(i & 31) * 4] = v;
    }

    int g  = threadIdx.x >> 5;
    int cg = threadIdx.x & 31;
    float4 bb = ((const float4*)b)[cg];
    float4 acc[8];
    #pragma unroll
    for (int r = 0; r < 8; ++r) acc[r] = bb;

    const float4* wv = (const float4*)w;   // [k][32] float4
    for (int kc = 0; kc < DD; kc += 32) {
        __syncthreads();
        for (int i = threadIdx.x; i < 32 * 32; i += 256)
            wb[i >> 5][i & 31] = wv[(size_t)(kc + (i >> 5)) * 32 + (i & 31)];
        __syncthreads();
        #pragma unroll 8
        for (int kk = 0; kk < 32; ++kk) {
            float4 wk = wb[kk][cg];
            #pragma unroll
            for (int r = 0; r < 8; ++r) {
                float xv = xs[g * 8 + r][kc + kk];
                acc[r].x += xv * wk.x; acc[r].y += xv * wk.y;
                acc[r].z += xv * wk.z; acc[r].w += xv * wk.w;
            }
        }
    }
    #pragma unroll
    for (int r = 0; r < 8; ++r) {
        int row = rbase + g * 8 + r;
        if (row < nrows) *(float4*)&y[(size_t)row * DD + cg * 4] = acc[r];
    }
}

// ---------------- histogram of dst for BOTH convs + per-edge rank -----------
__global__ __launch_bounds__(256) void k_hist2(const int* __restrict__ dst0, int E0p,
                                               const int* __restrict__ dst1, int E1p,
                                               int* __restrict__ cnt,
                                               int* __restrict__ rank, int N) {
    int e = blockIdx.x * 256 + threadIdx.x;
    if (e < E0p) rank[e] = atomicAdd(&cnt[dst0[e]], 1);
    else if (e - E0p < E1p) rank[e] = atomicAdd(&cnt[N + dst1[e - E0p]], 1);
}

// ---------------- 3-kernel exclusive scan over cnt[0..n) --------------------
__global__ __launch_bounds__(256) void k_scanA(const int* __restrict__ cnt,
                                               int* __restrict__ ex,
                                               int* __restrict__ bsum, int n) {
    __shared__ int s[256];
    int idx = blockIdx.x * 256 + threadIdx.x;
    int v = (idx < n) ? cnt[idx] : 0;
    s[threadIdx.x] = v;
    __syncthreads();
    for (int o = 1; o < 256; o <<= 1) {
        int t = (threadIdx.x >= o) ? s[threadIdx.x - o] : 0;
        __syncthreads();
        s[threadIdx.x] += t;
        __syncthreads();
    }
    if (idx < n) ex[idx] = s[threadIdx.x] - v;
    if (threadIdx.x == 255) bsum[blockIdx.x] = s[255];
}

__global__ __launch_bounds__(512) void k_scanB(int* __restrict__ bsum, int nb) {
    __shared__ int s[512];
    int v = (threadIdx.x < nb) ? bsum[threadIdx.x] : 0;
    s[threadIdx.x] = v;
    __syncthreads();
    for (int o = 1; o < 512; o <<= 1) {
        int t = (threadIdx.x >= o) ? s[threadIdx.x - o] : 0;
        __syncthreads();
        s[threadIdx.x] += t;
        __syncthreads();
    }
    if (threadIdx.x < nb) bsum[threadIdx.x] = s[threadIdx.x] - v;
}

__global__ __launch_bounds__(256) void k_scanC(const int* __restrict__ ex,
                                               const int* __restrict__ bsum,
                                               int* __restrict__ rowptr, int n) {
    int idx = blockIdx.x * 256 + threadIdx.x;
    if (idx < n) rowptr[idx] = ex[idx] + bsum[blockIdx.x];
}

// ---------------- CSR fill for BOTH convs (atomic-free via rank) ------------
__global__ __launch_bounds__(256) void k_fill2(const int* __restrict__ src0,
                                               const int* __restrict__ dst0, int E0p,
                                               const int* __restrict__ src1,
                                               const int* __restrict__ dst1, int E1p,
                                               const int* __restrict__ rowptr,
                                               const int* __restrict__ rank,
                                               int* __restrict__ ssrc, int N) {
    int e = blockIdx.x * 256 + threadIdx.x;
    if (e < E0p) {
        ssrc[rowptr[dst0[e]] + rank[e]] = src0[e];
    } else if (e - E0p < E1p) {
        int e1 = e - E0p;
        ssrc[rowptr[N + dst1[e1]] + rank[e]] = src1[e1];
    }
}

// ---------------- fused logit + online-softmax + aggregate + bias -----------
// ONE WAVE per node; lane holds features {2*lane, 2*lane+1} (same head).
__global__ __launch_bounds__(256) void k_agg(const float* __restrict__ xl,
                                             const int* __restrict__ rowptr,
                                             const int* __restrict__ cnt,
                                             const int* __restrict__ ssrc,
                                             const float* __restrict__ att,
                                             const float* __restrict__ bias,
                                             float* __restrict__ out, int n) {
    int node = __builtin_amdgcn_readfirstlane(blockIdx.x * 4 + (threadIdx.x >> 6));
    if (node >= n) return;
    int lane = threadIdx.x & 63;
    float2 attv = *(const float2*)&att[lane * 2];
    float2 xd   = *(const float2*)&xl[(size_t)node * DD + lane * 2];
    int rs  = rowptr[node];
    int deg = cnt[node];

    float m = -3.4e38f, den = 0.f;
    float accx = 0.f, accy = 0.f;
    int sA = (deg > 0) ? ssrc[rs] : 0;
    int sB = (deg > 1) ? ssrc[rs + 1] : 0;
    float2 vA = *(const float2*)&xl[(size_t)sA * DD + lane * 2];
    float2 vB = *(const float2*)&xl[(size_t)sB * DD + lane * 2];

    int k = 0;
    for (; k + 1 < deg; k += 2) {
        int sC = (k + 2 < deg) ? ssrc[rs + k + 2] : 0;
        int sD = (k + 3 < deg) ? ssrc[rs + k + 3] : 0;
        float2 vC = *(const float2*)&xl[(size_t)sC * DD + lane * 2];
        float2 vD = *(const float2*)&xl[(size_t)sD * DD + lane * 2];

        float tx = xd.x + vA.x, ty = xd.y + vA.y;
        tx = tx > 0.f ? tx : 0.2f * tx;
        ty = ty > 0.f ? ty : 0.2f * ty;
        float l0 = tx * attv.x + ty * attv.y;
        tx = xd.x + vB.x; ty = xd.y + vB.y;
        tx = tx > 0.f ? tx : 0.2f * tx;
        ty = ty > 0.f ? ty : 0.2f * ty;
        float l1 = tx * attv.x + ty * attv.y;
        #pragma unroll
        for (int o = 8; o; o >>= 1) {
            l0 += __shfl_xor(l0, o, 64);
            l1 += __shfl_xor(l1, o, 64);
        }
        float mn = fmaxf(fmaxf(m, l0), l1);
        float corr = __expf(m - mn);
        float w0 = __expf(l0 - mn);
        float w1 = __expf(l1 - mn);
        den  = den  * corr + w0 + w1;
        accx = accx * corr + w0 * vA.x + w1 * vB.x;
        accy = accy * corr + w0 * vA.y + w1 * vB.y;
        m = mn;
        sA = sC; sB = sD; vA = vC; vB = vD;
    }
    if (k < deg) {
        float tx = xd.x + vA.x, ty = xd.y + vA.y;
        tx = tx > 0.f ? tx : 0.2f * tx;
        ty = ty > 0.f ? ty : 0.2f * ty;
        float l0 = tx * attv.x + ty * attv.y;
        #pragma unroll
        for (int o = 8; o; o >>= 1) l0 += __shfl_xor(l0, o, 64);
        float mn = fmaxf(m, l0);
        float corr = __expf(m - mn);
        float w0 = __expf(l0 - mn);
        den  = den  * corr + w0;
        accx = accx * corr + w0 * vA.x;
        accy = accy * corr + w0 * vA.y;
    }

    float inv = (deg > 0) ? 1.f / den : 0.f;
    float2 o2;
    o2.x = accx * inv + bias[lane * 2];
    o2.y = accy * inv + bias[lane * 2 + 1];
    *(float2*)&out[(size_t)node * DD + lane * 2] = o2;
}

// ---------------- head: y = LN(x[:rows] @ w + b) * gamma + beta -------------
__global__ __launch_bounds__(128) void k_head(const float* __restrict__ x,
                                              const float* __restrict__ w,
                                              const float* __restrict__ b,
                                              const float* __restrict__ gamma,
                                              const float* __restrict__ beta,
                                              float* __restrict__ y) {
    int r = blockIdx.x, c = threadIdx.x;
    __shared__ float xr[DD];
    __shared__ float red[2];
    xr[c] = x[(size_t)r * DD + c];
    __syncthreads();
    float acc = b[c];
    #pragma unroll 4
    for (int k = 0; k < DD; ++k) acc += xr[k] * w[k * DD + c];
    float s = acc;
    #pragma unroll
    for (int o = 32; o; o >>= 1) s += __shfl_down(s, o);
    if ((c & 63) == 0) red[c >> 6] = s;
    __syncthreads();
    float mean = (red[0] + red[1]) * (1.f / 128.f);
    __syncthreads();
    float dv = acc - mean;
    float s2 = dv * dv;
    #pragma unroll
    for (int o = 32; o; o >>= 1) s2 += __shfl_down(s2, o);
    if ((c & 63) == 0) red[c >> 6] = s2;
    __syncthreads();
    float var = (red[0] + red[1]) * (1.f / 128.f);
    y[(size_t)r * DD + c] = dv / sqrtf(var + 1e-12f) * gamma[c] + beta[c];
}

extern "C" void kernel_launch(void* const* d_in, const int* in_sizes, int n_in,
                              void* d_out, int out_size, void* d_ws, size_t ws_size,
                              hipStream_t stream) {
    const float* embs  = (const float*)d_in[0];
    const float* w0    = (const float*)d_in[1];
    const float* b0    = (const float*)d_in[2];
    const float* att0  = (const float*)d_in[3];
    const float* bias0 = (const float*)d_in[4];
    const float* w1    = (const float*)d_in[5];
    const float* b1    = (const float*)d_in[6];
    const float* att1  = (const float*)d_in[7];
    const float* bias1 = (const float*)d_in[8];
    const float* wout  = (const float*)d_in[9];
    const float* bout  = (const float*)d_in[10];
    const float* gamma = (const float*)d_in[11];
    const float* beta  = (const float*)d_in[12];
    const int* ei0 = (const int*)d_in[13];
    const int* ei1 = (const int*)d_in[14];

    int N  = in_sizes[0] / DD;
    int E0 = in_sizes[13] / 2;
    int E1 = in_sizes[14] / 2;
    int N2 = 2 * N;

    // ---- workspace carve-up ----
    float* ws = (float*)d_ws;
    float* xl     = ws;                                   // N*128
    float* out    = xl + (size_t)N * DD;                  // N*128
    int*   ssrc   = (int*)(out + (size_t)N * DD);         // E0+E1
    int*   rank   = ssrc + (E0 + E1);                     // E0+E1
    int*   cnt    = rank + (E0 + E1);                     // 2N
    int*   rowptr = cnt + N2;                             // 2N
    int*   ex     = rowptr + N2;                          // 2N
    int*   bsum   = ex + N2;                              // 512

    int gLin   = (N + 63) / 64;
    int gScan  = (N2 + 255) / 256;          // 391 blocks <= 512-wide scanB
    int gAgg   = (N + 3) / 4;
    int gEdges = (E0 + E1 + 255) / 256;

    // ---- build CSR for both convs up front ----
    hipMemsetAsync(cnt, 0, (size_t)N2 * sizeof(int), stream);
    k_hist2<<<gEdges, 256, 0, stream>>>(ei0 + E0, E0, ei1 + E1, E1, cnt, rank, N);
    k_scanA<<<gScan, 256, 0, stream>>>(cnt, ex, bsum, N2);
    k_scanB<<<1, 512, 0, stream>>>(bsum, gScan);
    k_scanC<<<gScan, 256, 0, stream>>>(ex, bsum, rowptr, N2);
    k_fill2<<<gEdges, 256, 0, stream>>>(ei0, ei0 + E0, E0, ei1, ei1 + E1, E1,
                                        rowptr, rank, ssrc, N);

    // ---- conv0 ----
    k_linear<<<gLin, 256, 0, stream>>>(embs, w0, b0, xl, N, 0);
    k_agg<<<gAgg, 256, 0, stream>>>(xl, rowptr, cnt, ssrc, att0, bias0, out, N);

    // ---- conv1 (gelu fused into linear input load) ----
    k_linear<<<gLin, 256, 0, stream>>>(out, w1, b1, xl, N, 1);
    k_agg<<<gAgg, 256, 0, stream>>>(xl, rowptr + N, cnt + N, ssrc, att1, bias1,
                                    out, N);

    // ---- head ----
    k_head<<<1024, 128, 0, stream>>>(out, wout, bout, gamma, beta, (float*)d_out);
}

// Round 6
// 266.292 us; speedup vs baseline: 4.0585x; 1.0132x over previous
//
#include <hip/hip_runtime.h>
#include <math.h>

#define DD 128
#define NREP 8

// ---------------- replicated histogram of dst for BOTH convs + rank ---------
// rep = blockIdx&7 tracks the XCD round-robin so same-line atomics mostly stay
// in one XCD's L2 (kills cross-XCD dirty-line bounce). rank = within-replica
// order, recomputed in fill as rep = (gid>>8)&7.
__global__ __launch_bounds__(256) void k_hist2(const int* __restrict__ dst0, int E0p,
                                               const int* __restrict__ dst1, int E1p,
                                               int* __restrict__ cntR,
                                               int* __restrict__ rank,
                                               int N, int n2) {
    int e = blockIdx.x * 256 + threadIdx.x;
    int rep = blockIdx.x & (NREP - 1);
    if (e < E0p)
        rank[e] = atomicAdd(&cntR[(size_t)rep * n2 + dst0[e]], 1);
    else if (e - E0p < E1p)
        rank[e] = atomicAdd(&cntR[(size_t)rep * n2 + N + dst1[e - E0p]], 1);
}

// ---------------- scanA: 8-way per-key prefix + block scan ------------------
__global__ __launch_bounds__(256) void k_scanA(int* __restrict__ cntR, int n,
                                               int* __restrict__ deg,
                                               int* __restrict__ ex,
                                               int* __restrict__ bsum) {
    __shared__ int s[256];
    int idx = blockIdx.x * 256 + threadIdx.x;
    int v = 0;
    if (idx < n) {
        int run = 0;
        #pragma unroll
        for (int r = 0; r < NREP; ++r) {
            int c = cntR[(size_t)r * n + idx];
            cntR[(size_t)r * n + idx] = run;   // exclusive within-key offset
            run += c;
        }
        v = run;
        deg[idx] = run;
    }
    s[threadIdx.x] = v;
    __syncthreads();
    for (int o = 1; o < 256; o <<= 1) {
        int t = (threadIdx.x >= o) ? s[threadIdx.x - o] : 0;
        __syncthreads();
        s[threadIdx.x] += t;
        __syncthreads();
    }
    if (idx < n) ex[idx] = s[threadIdx.x] - v;
    if (threadIdx.x == 255) bsum[blockIdx.x] = s[255];
}

__global__ __launch_bounds__(512) void k_scanB(int* __restrict__ bsum, int nb) {
    __shared__ int s[512];
    int v = (threadIdx.x < nb) ? bsum[threadIdx.x] : 0;
    s[threadIdx.x] = v;
    __syncthreads();
    for (int o = 1; o < 512; o <<= 1) {
        int t = (threadIdx.x >= o) ? s[threadIdx.x - o] : 0;
        __syncthreads();
        s[threadIdx.x] += t;
        __syncthreads();
    }
    if (threadIdx.x < nb) bsum[threadIdx.x] = s[threadIdx.x] - v;
}

// rowptr = global scan; also fold rowptr into each replica offset so fill
// needs a single gather.
__global__ __launch_bounds__(256) void k_scanC(const int* __restrict__ ex,
                                               const int* __restrict__ bsum,
                                               int* __restrict__ rowptr,
                                               int* __restrict__ cntR, int n) {
    int idx = blockIdx.x * 256 + threadIdx.x;
    if (idx < n) {
        int rp = ex[idx] + bsum[blockIdx.x];
        rowptr[idx] = rp;
        #pragma unroll
        for (int r = 0; r < NREP; ++r) cntR[(size_t)r * n + idx] += rp;
    }
}

// ---------------- fused CSR-fill (one conv) + linear ------------------------
// Blocks [0, gFill) scatter edge sources into CSR slots; blocks [gFill, ...)
// run the LDS-tiled linear (64 rows x 128, one LDS float4 read -> 32 FMAs).
__global__ __launch_bounds__(256) void k_linfill(
        // linear part
        const float* __restrict__ x, const float* __restrict__ w,
        const float* __restrict__ b, float* __restrict__ y,
        int nrows, int apply_gelu, int gFill,
        // fill part
        const int* __restrict__ esrc, const int* __restrict__ edst, int nE,
        int keyOff, int gidBase, const int* __restrict__ repOff,
        const int* __restrict__ rank, int* __restrict__ ssrc, int n2) {
    __shared__ float  xs[64][DD];     // 32 KB
    __shared__ float4 wb[32][32];     // 16 KB

    if (blockIdx.x < gFill) {
        int e = blockIdx.x * 256 + threadIdx.x;
        if (e < nE) {
            int gid = gidBase + e;
            int rep = (gid >> 8) & (NREP - 1);
            int key = keyOff + edst[e];
            int pos = repOff[(size_t)rep * n2 + key] + rank[gid];
            ssrc[pos] = esrc[e];
        }
        return;
    }

    int blk = blockIdx.x - gFill;
    int rbase = blk * 64;
    for (int i = threadIdx.x; i < 64 * 32; i += 256) {
        int r = rbase + (i >> 5);
        float4 v = make_float4(0.f, 0.f, 0.f, 0.f);
        if (r < nrows) v = ((const float4*)x)[(size_t)r * 32 + (i & 31)];
        if (apply_gelu) {
            v.x = 0.5f * v.x * (1.f + erff(v.x * 0.70710678f));
            v.y = 0.5f * v.y * (1.f + erff(v.y * 0.70710678f));
            v.z = 0.5f * v.z * (1.f + erff(v.z * 0.70710678f));
            v.w = 0.5f * v.w * (1.f + erff(v.w * 0.70710678f));
        }
        *(float4*)&xs[i >> 5][(i & 31) * 4] = v;
    }

    int g  = threadIdx.x >> 5;
    int cg = threadIdx.x & 31;
    float4 bb = ((const float4*)b)[cg];
    float4 acc[8];
    #pragma unroll
    for (int r = 0; r < 8; ++r) acc[r] = bb;

    const float4* wv = (const float4*)w;   // [k][32] float4
    for (int kc = 0; kc < DD; kc += 32) {
        __syncthreads();
        for (int i = threadIdx.x; i < 32 * 32; i += 256)
            wb[i >> 5][i & 31] = wv[(size_t)(kc + (i >> 5)) * 32 + (i & 31)];
        __syncthreads();
        #pragma unroll 8
        for (int kk = 0; kk < 32; ++kk) {
            float4 wk = wb[kk][cg];
            #pragma unroll
            for (int r = 0; r < 8; ++r) {
                float xv = xs[g * 8 + r][kc + kk];
                acc[r].x += xv * wk.x; acc[r].y += xv * wk.y;
                acc[r].z += xv * wk.z; acc[r].w += xv * wk.w;
            }
        }
    }
    #pragma unroll
    for (int r = 0; r < 8; ++r) {
        int row = rbase + g * 8 + r;
        if (row < nrows) *(float4*)&y[(size_t)row * DD + cg * 4] = acc[r];
    }
}

// ---------------- fused logit + online-softmax + aggregate + bias -----------
// ONE WAVE per node; lane holds features {2*lane, 2*lane+1} (same head).
__global__ __launch_bounds__(256) void k_agg(const float* __restrict__ xl,
                                             const int* __restrict__ rowptr,
                                             const int* __restrict__ deg_,
                                             const int* __restrict__ ssrc,
                                             const float* __restrict__ att,
                                             const float* __restrict__ bias,
                                             float* __restrict__ out, int n) {
    int node = __builtin_amdgcn_readfirstlane(blockIdx.x * 4 + (threadIdx.x >> 6));
    if (node >= n) return;
    int lane = threadIdx.x & 63;
    float2 attv = *(const float2*)&att[lane * 2];
    float2 xd   = *(const float2*)&xl[(size_t)node * DD + lane * 2];
    int rs  = rowptr[node];
    int deg = deg_[node];

    float m = -3.4e38f, den = 0.f;
    float accx = 0.f, accy = 0.f;
    int sA = (deg > 0) ? ssrc[rs] : 0;
    int sB = (deg > 1) ? ssrc[rs + 1] : 0;
    float2 vA = *(const float2*)&xl[(size_t)sA * DD + lane * 2];
    float2 vB = *(const float2*)&xl[(size_t)sB * DD + lane * 2];

    int k = 0;
    for (; k + 1 < deg; k += 2) {
        int sC = (k + 2 < deg) ? ssrc[rs + k + 2] : 0;
        int sD = (k + 3 < deg) ? ssrc[rs + k + 3] : 0;
        float2 vC = *(const float2*)&xl[(size_t)sC * DD + lane * 2];
        float2 vD = *(const float2*)&xl[(size_t)sD * DD + lane * 2];

        float tx = xd.x + vA.x, ty = xd.y + vA.y;
        tx = tx > 0.f ? tx : 0.2f * tx;
        ty = ty > 0.f ? ty : 0.2f * ty;
        float l0 = tx * attv.x + ty * attv.y;
        tx = xd.x + vB.x; ty = xd.y + vB.y;
        tx = tx > 0.f ? tx : 0.2f * tx;
        ty = ty > 0.f ? ty : 0.2f * ty;
        float l1 = tx * attv.x + ty * attv.y;
        #pragma unroll
        for (int o = 8; o; o >>= 1) {
            l0 += __shfl_xor(l0, o, 64);
            l1 += __shfl_xor(l1, o, 64);
        }
        float mn = fmaxf(fmaxf(m, l0), l1);
        float corr = __expf(m - mn);
        float w0 = __expf(l0 - mn);
        float w1 = __expf(l1 - mn);
        den  = den  * corr + w0 + w1;
        accx = accx * corr + w0 * vA.x + w1 * vB.x;
        accy = accy * corr + w0 * vA.y + w1 * vB.y;
        m = mn;
        sA = sC; sB = sD; vA = vC; vB = vD;
    }
    if (k < deg) {
        float tx = xd.x + vA.x, ty = xd.y + vA.y;
        tx = tx > 0.f ? tx : 0.2f * tx;
        ty = ty > 0.f ? ty : 0.2f * ty;
        float l0 = tx * attv.x + ty * attv.y;
        #pragma unroll
        for (int o = 8; o; o >>= 1) l0 += __shfl_xor(l0, o, 64);
        float mn = fmaxf(m, l0);
        float corr = __expf(m - mn);
        float w0 = __expf(l0 - mn);
        den  = den  * corr + w0;
        accx = accx * corr + w0 * vA.x;
        accy = accy * corr + w0 * vA.y;
    }

    float inv = (deg > 0) ? 1.f / den : 0.f;
    float2 o2;
    o2.x = accx * inv + bias[lane * 2];
    o2.y = accy * inv + bias[lane * 2 + 1];
    *(float2*)&out[(size_t)node * DD + lane * 2] = o2;
}

// ---------------- head: y = LN(x[:rows] @ w + b) * gamma + beta -------------
__global__ __launch_bounds__(128) void k_head(const float* __restrict__ x,
                                              const float* __restrict__ w,
                                              const float* __restrict__ b,
                                              const float* __restrict__ gamma,
                                              const float* __restrict__ beta,
                                              float* __restrict__ y) {
    int r = blockIdx.x, c = threadIdx.x;
    __shared__ float xr[DD];
    __shared__ float red[2];
    xr[c] = x[(size_t)r * DD + c];
    __syncthreads();
    float acc = b[c];
    #pragma unroll 4
    for (int k = 0; k < DD; ++k) acc += xr[k] * w[k * DD + c];
    float s = acc;
    #pragma unroll
    for (int o = 32; o; o >>= 1) s += __shfl_down(s, o);
    if ((c & 63) == 0) red[c >> 6] = s;
    __syncthreads();
    float mean = (red[0] + red[1]) * (1.f / 128.f);
    __syncthreads();
    float dv = acc - mean;
    float s2 = dv * dv;
    #pragma unroll
    for (int o = 32; o; o >>= 1) s2 += __shfl_down(s2, o);
    if ((c & 63) == 0) red[c >> 6] = s2;
    __syncthreads();
    float var = (red[0] + red[1]) * (1.f / 128.f);
    y[(size_t)r * DD + c] = dv / sqrtf(var + 1e-12f) * gamma[c] + beta[c];
}

extern "C" void kernel_launch(void* const* d_in, const int* in_sizes, int n_in,
                              void* d_out, int out_size, void* d_ws, size_t ws_size,
                              hipStream_t stream) {
    const float* embs  = (const float*)d_in[0];
    const float* w0    = (const float*)d_in[1];
    const float* b0    = (const float*)d_in[2];
    const float* att0  = (const float*)d_in[3];
    const float* bias0 = (const float*)d_in[4];
    const float* w1    = (const float*)d_in[5];
    const float* b1    = (const float*)d_in[6];
    const float* att1  = (const float*)d_in[7];
    const float* bias1 = (const float*)d_in[8];
    const float* wout  = (const float*)d_in[9];
    const float* bout  = (const float*)d_in[10];
    const float* gamma = (const float*)d_in[11];
    const float* beta  = (const float*)d_in[12];
    const int* ei0 = (const int*)d_in[13];
    const int* ei1 = (const int*)d_in[14];

    int N  = in_sizes[0] / DD;
    int E0 = in_sizes[13] / 2;
    int E1 = in_sizes[14] / 2;
    int N2 = 2 * N;

    // ---- workspace carve-up ----
    float* ws = (float*)d_ws;
    float* xl     = ws;                                   // N*128
    float* out    = xl + (size_t)N * DD;                  // N*128
    int*   ssrc   = (int*)(out + (size_t)N * DD);         // E0+E1
    int*   rank   = ssrc + (E0 + E1);                     // E0+E1
    int*   cntR   = rank + (E0 + E1);                     // NREP*2N
    int*   degA   = cntR + (size_t)NREP * N2;             // 2N
    int*   rowptr = degA + N2;                            // 2N
    int*   ex     = rowptr + N2;                          // 2N
    int*   bsum   = ex + N2;                              // 512

    int gLin   = (N + 63) / 64;
    int gScan  = (N2 + 255) / 256;          // 391 blocks <= 512-wide scanB
    int gAgg   = (N + 3) / 4;
    int gEdges = (E0 + E1 + 255) / 256;
    int gF0    = (E0 + 255) / 256;
    int gF1    = (E1 + 255) / 256;

    // ---- CSR build: replicated hist + scan ----
    hipMemsetAsync(cntR, 0, (size_t)NREP * N2 * sizeof(int), stream);
    k_hist2<<<gEdges, 256, 0, stream>>>(ei0 + E0, E0, ei1 + E1, E1, cntR, rank, N, N2);
    k_scanA<<<gScan, 256, 0, stream>>>(cntR, N2, degA, ex, bsum);
    k_scanB<<<1, 512, 0, stream>>>(bsum, gScan);
    k_scanC<<<gScan, 256, 0, stream>>>(ex, bsum, rowptr, cntR, N2);

    // ---- conv0: fill0 || linear0, then aggregate ----
    k_linfill<<<gF0 + gLin, 256, 0, stream>>>(embs, w0, b0, xl, N, 0, gF0,
                                              ei0, ei0 + E0, E0, 0, 0,
                                              cntR, rank, ssrc, N2);
    k_agg<<<gAgg, 256, 0, stream>>>(xl, rowptr, degA, ssrc, att0, bias0, out, N);

    // ---- conv1: fill1 || linear1(gelu), then aggregate ----
    k_linfill<<<gF1 + gLin, 256, 0, stream>>>(out, w1, b1, xl, N, 1, gF1,
                                              ei1, ei1 + E1, E1, N, E0,
                                              cntR, rank, ssrc, N2);
    k_agg<<<gAgg, 256, 0, stream>>>(xl, rowptr + N, degA + N, ssrc, att1, bias1,
                                    out, N);

    // ---- head ----
    k_head<<<1024, 128, 0, stream>>>(out, wout, bout, gamma, beta, (float*)d_out);
}

// Round 7
// 242.703 us; speedup vs baseline: 4.4530x; 1.0972x over previous
//
#include <hip/hip_runtime.h>
#include <math.h>

#define DD 128
#define NREP 8

__device__ __forceinline__ unsigned bf16rne(float f) {
    unsigned u = __float_as_uint(f);
    return (u + 0x7FFFu + ((u >> 16) & 1u)) >> 16;
}
__device__ __forceinline__ float2 bf2f(unsigned u) {
    float2 r;
    r.x = __uint_as_float(u << 16);
    r.y = __uint_as_float(u & 0xFFFF0000u);
    return r;
}

// ---------------- replicated histogram of dst for BOTH convs + rank ---------
__global__ __launch_bounds__(256) void k_hist2(const int* __restrict__ dst0, int E0p,
                                               const int* __restrict__ dst1, int E1p,
                                               int* __restrict__ cntR,
                                               int* __restrict__ rank,
                                               int N, int n2) {
    int e = blockIdx.x * 256 + threadIdx.x;
    int rep = blockIdx.x & (NREP - 1);
    if (e < E0p)
        rank[e] = atomicAdd(&cntR[(size_t)rep * n2 + dst0[e]], 1);
    else if (e - E0p < E1p)
        rank[e] = atomicAdd(&cntR[(size_t)rep * n2 + N + dst1[e - E0p]], 1);
}

// ---------------- scanA: 8-way per-key prefix + block scan ------------------
__global__ __launch_bounds__(256) void k_scanA(int* __restrict__ cntR, int n,
                                               int* __restrict__ deg,
                                               int* __restrict__ ex,
                                               int* __restrict__ bsum) {
    __shared__ int s[256];
    int idx = blockIdx.x * 256 + threadIdx.x;
    int v = 0;
    if (idx < n) {
        int run = 0;
        #pragma unroll
        for (int r = 0; r < NREP; ++r) {
            int c = cntR[(size_t)r * n + idx];
            cntR[(size_t)r * n + idx] = run;
            run += c;
        }
        v = run;
        deg[idx] = run;
    }
    s[threadIdx.x] = v;
    __syncthreads();
    for (int o = 1; o < 256; o <<= 1) {
        int t = (threadIdx.x >= o) ? s[threadIdx.x - o] : 0;
        __syncthreads();
        s[threadIdx.x] += t;
        __syncthreads();
    }
    if (idx < n) ex[idx] = s[threadIdx.x] - v;
    if (threadIdx.x == 255) bsum[blockIdx.x] = s[255];
}

__global__ __launch_bounds__(512) void k_scanB(int* __restrict__ bsum, int nb) {
    __shared__ int s[512];
    int v = (threadIdx.x < nb) ? bsum[threadIdx.x] : 0;
    s[threadIdx.x] = v;
    __syncthreads();
    for (int o = 1; o < 512; o <<= 1) {
        int t = (threadIdx.x >= o) ? s[threadIdx.x - o] : 0;
        __syncthreads();
        s[threadIdx.x] += t;
        __syncthreads();
    }
    if (threadIdx.x < nb) bsum[threadIdx.x] = s[threadIdx.x] - v;
}

__global__ __launch_bounds__(256) void k_scanC(const int* __restrict__ ex,
                                               const int* __restrict__ bsum,
                                               int* __restrict__ rowptr,
                                               int* __restrict__ cntR, int n) {
    int idx = blockIdx.x * 256 + threadIdx.x;
    if (idx < n) {
        int rp = ex[idx] + bsum[blockIdx.x];
        rowptr[idx] = rp;
        #pragma unroll
        for (int r = 0; r < NREP; ++r) cntR[(size_t)r * n + idx] += rp;
    }
}

// ---------------- fused CSR-fill (conv0) + linear (bf16 output) -------------
__global__ __launch_bounds__(256) void k_linfill(
        const float* __restrict__ x, const float* __restrict__ w,
        const float* __restrict__ b, unsigned* __restrict__ y,
        int nrows, int apply_gelu, int gFill,
        const int* __restrict__ esrc, const int* __restrict__ edst, int nE,
        int keyOff, int gidBase, const int* __restrict__ repOff,
        const int* __restrict__ rank, int* __restrict__ ssrc, int n2) {
    __shared__ float  xs[64][DD];     // 32 KB
    __shared__ float4 wb[32][32];     // 16 KB

    if (blockIdx.x < gFill) {
        int e = blockIdx.x * 256 + threadIdx.x;
        if (e < nE) {
            int gid = gidBase + e;
            int rep = (gid >> 8) & (NREP - 1);
            int key = keyOff + edst[e];
            int pos = repOff[(size_t)rep * n2 + key] + rank[gid];
            ssrc[pos] = esrc[e];
        }
        return;
    }

    int blk = blockIdx.x - gFill;
    int rbase = blk * 64;
    for (int i = threadIdx.x; i < 64 * 32; i += 256) {
        int r = rbase + (i >> 5);
        float4 v = make_float4(0.f, 0.f, 0.f, 0.f);
        if (r < nrows) v = ((const float4*)x)[(size_t)r * 32 + (i & 31)];
        if (apply_gelu) {
            v.x = 0.5f * v.x * (1.f + erff(v.x * 0.70710678f));
            v.y = 0.5f * v.y * (1.f + erff(v.y * 0.70710678f));
            v.z = 0.5f * v.z * (1.f + erff(v.z * 0.70710678f));
            v.w = 0.5f * v.w * (1.f + erff(v.w * 0.70710678f));
        }
        *(float4*)&xs[i >> 5][(i & 31) * 4] = v;
    }

    int g  = threadIdx.x >> 5;
    int cg = threadIdx.x & 31;
    float4 bb = ((const float4*)b)[cg];
    float4 acc[8];
    #pragma unroll
    for (int r = 0; r < 8; ++r) acc[r] = bb;

    const float4* wv = (const float4*)w;   // [k][32] float4
    for (int kc = 0; kc < DD; kc += 32) {
        __syncthreads();
        for (int i = threadIdx.x; i < 32 * 32; i += 256)
            wb[i >> 5][i & 31] = wv[(size_t)(kc + (i >> 5)) * 32 + (i & 31)];
        __syncthreads();
        #pragma unroll 8
        for (int kk = 0; kk < 32; ++kk) {
            float4 wk = wb[kk][cg];
            #pragma unroll
            for (int r = 0; r < 8; ++r) {
                float xv = xs[g * 8 + r][kc + kk];
                acc[r].x += xv * wk.x; acc[r].y += xv * wk.y;
                acc[r].z += xv * wk.z; acc[r].w += xv * wk.w;
            }
        }
    }
    #pragma unroll
    for (int r = 0; r < 8; ++r) {
        int row = rbase + g * 8 + r;
        if (row < nrows) {
            uint2 p;
            p.x = bf16rne(acc[r].x) | (bf16rne(acc[r].y) << 16);
            p.y = bf16rne(acc[r].z) | (bf16rne(acc[r].w) << 16);
            ((uint2*)y)[(size_t)row * 32 + cg] = p;
        }
    }
}

// ---------------- fused logit + online-softmax + aggregate + bias -----------
// Optional leading gFill blocks scatter the NEXT conv's CSR (hidden under the
// L3-bound gather). ONE WAVE per node; lane holds features {2l, 2l+1}.
__global__ __launch_bounds__(256) void k_agg(const unsigned* __restrict__ xl,
                                             const int* __restrict__ rowptr,
                                             const int* __restrict__ deg_,
                                             const int* __restrict__ ssrc,
                                             const float* __restrict__ att,
                                             const float* __restrict__ bias,
                                             float* __restrict__ out, int n,
                                             int gFill,
                                             const int* __restrict__ esrc,
                                             const int* __restrict__ edst, int nEf,
                                             int keyOff, int gidBase,
                                             const int* __restrict__ repOff,
                                             const int* __restrict__ rank,
                                             int* __restrict__ ssrcW, int n2) {
    if (blockIdx.x < gFill) {
        int e = blockIdx.x * 256 + threadIdx.x;
        if (e < nEf) {
            int gid = gidBase + e;
            int rep = (gid >> 8) & (NREP - 1);
            int key = keyOff + edst[e];
            int pos = repOff[(size_t)rep * n2 + key] + rank[gid];
            ssrcW[pos] = esrc[e];
        }
        return;
    }
    int node = __builtin_amdgcn_readfirstlane((blockIdx.x - gFill) * 4 +
                                              (threadIdx.x >> 6));
    if (node >= n) return;
    int lane = threadIdx.x & 63;
    float2 attv = *(const float2*)&att[lane * 2];
    float2 xd = bf2f(xl[(size_t)node * 64 + lane]);
    int rs  = rowptr[node];
    int deg = deg_[node];

    float m = -3.4e38f, den = 0.f;
    float accx = 0.f, accy = 0.f;
    int sA = (deg > 0) ? ssrc[rs] : 0;
    int sB = (deg > 1) ? ssrc[rs + 1] : 0;
    unsigned uA = xl[(size_t)sA * 64 + lane];
    unsigned uB = xl[(size_t)sB * 64 + lane];

    int k = 0;
    for (; k + 1 < deg; k += 2) {
        int sC = (k + 2 < deg) ? ssrc[rs + k + 2] : 0;
        int sD = (k + 3 < deg) ? ssrc[rs + k + 3] : 0;
        unsigned uC = xl[(size_t)sC * 64 + lane];
        unsigned uD = xl[(size_t)sD * 64 + lane];
        float2 vA = bf2f(uA), vB = bf2f(uB);

        float tx = xd.x + vA.x, ty = xd.y + vA.y;
        tx = tx > 0.f ? tx : 0.2f * tx;
        ty = ty > 0.f ? ty : 0.2f * ty;
        float l0 = tx * attv.x + ty * attv.y;
        tx = xd.x + vB.x; ty = xd.y + vB.y;
        tx = tx > 0.f ? tx : 0.2f * tx;
        ty = ty > 0.f ? ty : 0.2f * ty;
        float l1 = tx * attv.x + ty * attv.y;
        #pragma unroll
        for (int o = 8; o; o >>= 1) {
            l0 += __shfl_xor(l0, o, 64);
            l1 += __shfl_xor(l1, o, 64);
        }
        float mn = fmaxf(fmaxf(m, l0), l1);
        float corr = __expf(m - mn);
        float w0 = __expf(l0 - mn);
        float w1 = __expf(l1 - mn);
        den  = den  * corr + w0 + w1;
        accx = accx * corr + w0 * vA.x + w1 * vB.x;
        accy = accy * corr + w0 * vA.y + w1 * vB.y;
        m = mn;
        sA = sC; sB = sD; uA = uC; uB = uD;
    }
    if (k < deg) {
        float2 vA = bf2f(uA);
        float tx = xd.x + vA.x, ty = xd.y + vA.y;
        tx = tx > 0.f ? tx : 0.2f * tx;
        ty = ty > 0.f ? ty : 0.2f * ty;
        float l0 = tx * attv.x + ty * attv.y;
        #pragma unroll
        for (int o = 8; o; o >>= 1) l0 += __shfl_xor(l0, o, 64);
        float mn = fmaxf(m, l0);
        float corr = __expf(m - mn);
        float w0 = __expf(l0 - mn);
        den  = den  * corr + w0;
        accx = accx * corr + w0 * vA.x;
        accy = accy * corr + w0 * vA.y;
    }

    float inv = (deg > 0) ? 1.f / den : 0.f;
    float2 o2;
    o2.x = accx * inv + bias[lane * 2];
    o2.y = accy * inv + bias[lane * 2 + 1];
    *(float2*)&out[(size_t)node * DD + lane * 2] = o2;
}

// ---------------- head: y = LN(x[:rows] @ w + b) * gamma + beta -------------
__global__ __launch_bounds__(128) void k_head(const float* __restrict__ x,
                                              const float* __restrict__ w,
                                              const float* __restrict__ b,
                                              const float* __restrict__ gamma,
                                              const float* __restrict__ beta,
                                              float* __restrict__ y) {
    int r = blockIdx.x, c = threadIdx.x;
    __shared__ float xr[DD];
    __shared__ float red[2];
    xr[c] = x[(size_t)r * DD + c];
    __syncthreads();
    float acc = b[c];
    #pragma unroll 4
    for (int k = 0; k < DD; ++k) acc += xr[k] * w[k * DD + c];
    float s = acc;
    #pragma unroll
    for (int o = 32; o; o >>= 1) s += __shfl_down(s, o);
    if ((c & 63) == 0) red[c >> 6] = s;
    __syncthreads();
    float mean = (red[0] + red[1]) * (1.f / 128.f);
    __syncthreads();
    float dv = acc - mean;
    float s2 = dv * dv;
    #pragma unroll
    for (int o = 32; o; o >>= 1) s2 += __shfl_down(s2, o);
    if ((c & 63) == 0) red[c >> 6] = s2;
    __syncthreads();
    float var = (red[0] + red[1]) * (1.f / 128.f);
    y[(size_t)r * DD + c] = dv / sqrtf(var + 1e-12f) * gamma[c] + beta[c];
}

extern "C" void kernel_launch(void* const* d_in, const int* in_sizes, int n_in,
                              void* d_out, int out_size, void* d_ws, size_t ws_size,
                              hipStream_t stream) {
    const float* embs  = (const float*)d_in[0];
    const float* w0    = (const float*)d_in[1];
    const float* b0    = (const float*)d_in[2];
    const float* att0  = (const float*)d_in[3];
    const float* bias0 = (const float*)d_in[4];
    const float* w1    = (const float*)d_in[5];
    const float* b1    = (const float*)d_in[6];
    const float* att1  = (const float*)d_in[7];
    const float* bias1 = (const float*)d_in[8];
    const float* wout  = (const float*)d_in[9];
    const float* bout  = (const float*)d_in[10];
    const float* gamma = (const float*)d_in[11];
    const float* beta  = (const float*)d_in[12];
    const int* ei0 = (const int*)d_in[13];
    const int* ei1 = (const int*)d_in[14];

    int N  = in_sizes[0] / DD;
    int E0 = in_sizes[13] / 2;
    int E1 = in_sizes[14] / 2;
    int N2 = 2 * N;

    // ---- workspace carve-up ----
    unsigned* xl  = (unsigned*)d_ws;                      // N*64 u32 (bf16 pairs)
    float* out    = (float*)(xl + (size_t)N * 64);        // N*128 f32
    int*   ssrc   = (int*)(out + (size_t)N * DD);         // E0+E1
    int*   rank   = ssrc + (E0 + E1);                     // E0+E1
    int*   cntR   = rank + (E0 + E1);                     // NREP*2N
    int*   degA   = cntR + (size_t)NREP * N2;             // 2N
    int*   rowptr = degA + N2;                            // 2N
    int*   ex     = rowptr + N2;                          // 2N
    int*   bsum   = ex + N2;                              // 512

    int gLin   = (N + 63) / 64;
    int gScan  = (N2 + 255) / 256;
    int gAgg   = (N + 3) / 4;
    int gEdges = (E0 + E1 + 255) / 256;
    int gF0    = (E0 + 255) / 256;
    int gF1    = (E1 + 255) / 256;

    // ---- CSR build: replicated hist + scan ----
    hipMemsetAsync(cntR, 0, (size_t)NREP * N2 * sizeof(int), stream);
    k_hist2<<<gEdges, 256, 0, stream>>>(ei0 + E0, E0, ei1 + E1, E1, cntR, rank, N, N2);
    k_scanA<<<gScan, 256, 0, stream>>>(cntR, N2, degA, ex, bsum);
    k_scanB<<<1, 512, 0, stream>>>(bsum, gScan);
    k_scanC<<<gScan, 256, 0, stream>>>(ex, bsum, rowptr, cntR, N2);

    // ---- conv0: fill0 || linear0, then aggregate (fill1 hidden under it) ----
    k_linfill<<<gF0 + gLin, 256, 0, stream>>>(embs, w0, b0, xl, N, 0, gF0,
                                              ei0, ei0 + E0, E0, 0, 0,
                                              cntR, rank, ssrc, N2);
    k_agg<<<gF1 + gAgg, 256, 0, stream>>>(xl, rowptr, degA, ssrc, att0, bias0,
                                          out, N, gF1,
                                          ei1, ei1 + E1, E1, N, E0,
                                          cntR, rank, ssrc, N2);

    // ---- conv1: linear1(gelu), then aggregate ----
    k_linfill<<<gLin, 256, 0, stream>>>(out, w1, b1, xl, N, 1, 0,
                                        nullptr, nullptr, 0, 0, 0,
                                        cntR, rank, ssrc, N2);
    k_agg<<<gAgg, 256, 0, stream>>>(xl, rowptr + N, degA + N, ssrc, att1, bias1,
                                    out, N, 0,
                                    nullptr, nullptr, 0, 0, 0,
                                    cntR, rank, ssrc, N2);

    // ---- head ----
    k_head<<<1024, 128, 0, stream>>>(out, wout, bout, gamma, beta, (float*)d_out);
}

// Round 8
// 131.477 us; speedup vs baseline: 8.2201x; 1.8460x over previous
//
#include <hip/hip_runtime.h>
#include <math.h>

#define DD 128

__device__ __forceinline__ unsigned bf16rne(float f) {
    unsigned u = __float_as_uint(f);
    return (u + 0x7FFFu + ((u >> 16) & 1u)) >> 16;
}
__device__ __forceinline__ float2 bf2f(unsigned u) {
    float2 r;
    r.x = __uint_as_float(u << 16);
    r.y = __uint_as_float(u & 0xFFFF0000u);
    return r;
}

// ---- mark live nodes: srcs of conv1 edges with dst<BS, plus nodes [0,BS) ----
__global__ __launch_bounds__(256) void k_mark(const int* __restrict__ src1,
                                              const int* __restrict__ dst1,
                                              int E1, int BS,
                                              int* __restrict__ mask) {
    int base = blockIdx.x * 1024 + threadIdx.x;
    #pragma unroll
    for (int j = 0; j < 4; ++j) {
        int e = base + j * 256;
        if (e < E1) {
            int d = dst1[e];
            if (d < BS) mask[src1[e]] = 1;
        }
    }
    int g = blockIdx.x * 256 + threadIdx.x;
    if (g < BS) mask[g] = 1;
}

// ---- generic block scan: ex = excl-scan(in) within block, bsum = block total
__global__ __launch_bounds__(256) void k_scanA(const int* __restrict__ in, int n,
                                               int* __restrict__ ex,
                                               int* __restrict__ bsum) {
    __shared__ int s[256];
    int idx = blockIdx.x * 256 + threadIdx.x;
    int v = (idx < n) ? in[idx] : 0;
    s[threadIdx.x] = v;
    __syncthreads();
    for (int o = 1; o < 256; o <<= 1) {
        int t = (threadIdx.x >= o) ? s[threadIdx.x - o] : 0;
        __syncthreads();
        s[threadIdx.x] += t;
        __syncthreads();
    }
    if (idx < n) ex[idx] = s[threadIdx.x] - v;
    if (threadIdx.x == 255) bsum[blockIdx.x] = s[255];
}

__global__ __launch_bounds__(256) void k_scanB(int* __restrict__ bsum, int nb) {
    __shared__ int s[256];
    int v = (threadIdx.x < nb) ? bsum[threadIdx.x] : 0;
    s[threadIdx.x] = v;
    __syncthreads();
    for (int o = 1; o < 256; o <<= 1) {
        int t = (threadIdx.x >= o) ? s[threadIdx.x - o] : 0;
        __syncthreads();
        s[threadIdx.x] += t;
        __syncthreads();
    }
    if (threadIdx.x < nb) bsum[threadIdx.x] = s[threadIdx.x] - v;
}

__global__ __launch_bounds__(256) void k_scanC(const int* __restrict__ ex,
                                               const int* __restrict__ bsum,
                                               int* __restrict__ rowptr, int n) {
    int idx = blockIdx.x * 256 + threadIdx.x;
    if (idx < n) rowptr[idx] = ex[idx] + bsum[blockIdx.x];
}

// ---- mask scan finalize: livelist compaction + nLive ------------------------
__global__ __launch_bounds__(256) void k_mscanC(const int* __restrict__ mask,
                                                const int* __restrict__ ex,
                                                const int* __restrict__ bsum,
                                                int* __restrict__ livelist,
                                                int* __restrict__ nLive, int n) {
    int idx = blockIdx.x * 256 + threadIdx.x;
    if (idx < n) {
        int v = ex[idx] + bsum[blockIdx.x];
        if (mask[idx]) livelist[v] = idx;
        if (idx == n - 1) *nLive = v + mask[idx];
    }
}

// ---- F1: filtered hist (conv0 live-dst + conv1 dst<BS) || linear0 ----------
__global__ __launch_bounds__(256) void k_histlin(
        const float* __restrict__ x, const float* __restrict__ w,
        const float* __restrict__ b, unsigned* __restrict__ y, int nrows,
        int gH0, int gH1,
        const int* __restrict__ dst0, int E0,
        const int* __restrict__ dst1, int E1, int BS,
        const int* __restrict__ mask, int* __restrict__ cnt,
        int* __restrict__ rank, int N) {
    __shared__ float  xs[64][DD];     // 32 KB
    __shared__ float4 wb[32][32];     // 16 KB

    if (blockIdx.x < gH0) {
        int base = blockIdx.x * 1024 + threadIdx.x;
        #pragma unroll
        for (int j = 0; j < 4; ++j) {
            int e = base + j * 256;
            if (e < E0) {
                int d = dst0[e];
                if (mask[d]) rank[e] = atomicAdd(&cnt[d], 1);
            }
        }
        return;
    }
    if (blockIdx.x < gH0 + gH1) {
        int base = (blockIdx.x - gH0) * 1024 + threadIdx.x;
        #pragma unroll
        for (int j = 0; j < 4; ++j) {
            int e = base + j * 256;
            if (e < E1) {
                int d = dst1[e];
                if (d < BS) rank[E0 + e] = atomicAdd(&cnt[N + d], 1);
            }
        }
        return;
    }

    int blk = blockIdx.x - gH0 - gH1;
    int rbase = blk * 64;
    for (int i = threadIdx.x; i < 64 * 32; i += 256) {
        int r = rbase + (i >> 5);
        float4 v = make_float4(0.f, 0.f, 0.f, 0.f);
        if (r < nrows) v = ((const float4*)x)[(size_t)r * 32 + (i & 31)];
        *(float4*)&xs[i >> 5][(i & 31) * 4] = v;
    }
    int g  = threadIdx.x >> 5;
    int cg = threadIdx.x & 31;
    float4 bb = ((const float4*)b)[cg];
    float4 acc[8];
    #pragma unroll
    for (int r = 0; r < 8; ++r) acc[r] = bb;
    const float4* wv = (const float4*)w;
    for (int kc = 0; kc < DD; kc += 32) {
        __syncthreads();
        for (int i = threadIdx.x; i < 32 * 32; i += 256)
            wb[i >> 5][i & 31] = wv[(size_t)(kc + (i >> 5)) * 32 + (i & 31)];
        __syncthreads();
        #pragma unroll 8
        for (int kk = 0; kk < 32; ++kk) {
            float4 wk = wb[kk][cg];
            #pragma unroll
            for (int r = 0; r < 8; ++r) {
                float xv = xs[g * 8 + r][kc + kk];
                acc[r].x += xv * wk.x; acc[r].y += xv * wk.y;
                acc[r].z += xv * wk.z; acc[r].w += xv * wk.w;
            }
        }
    }
    #pragma unroll
    for (int r = 0; r < 8; ++r) {
        int row = rbase + g * 8 + r;
        if (row < nrows) {
            uint2 p;
            p.x = bf16rne(acc[r].x) | (bf16rne(acc[r].y) << 16);
            p.y = bf16rne(acc[r].z) | (bf16rne(acc[r].w) << 16);
            ((uint2*)y)[(size_t)row * 32 + cg] = p;
        }
    }
}

// ---- F2: CSR fill for live conv0 edges + conv1 dst<BS edges ----------------
__global__ __launch_bounds__(256) void k_fill(const int* __restrict__ src0,
                                              const int* __restrict__ dst0, int E0,
                                              const int* __restrict__ src1,
                                              const int* __restrict__ dst1, int E1,
                                              int BS, int gF0,
                                              const int* __restrict__ mask,
                                              const int* __restrict__ rowptr,
                                              const int* __restrict__ rank,
                                              int* __restrict__ ssrc, int N) {
    if (blockIdx.x < gF0) {
        int base = blockIdx.x * 1024 + threadIdx.x;
        #pragma unroll
        for (int j = 0; j < 4; ++j) {
            int e = base + j * 256;
            if (e < E0) {
                int d = dst0[e];
                if (mask[d]) ssrc[rowptr[d] + rank[e]] = src0[e];
            }
        }
    } else {
        int base = (blockIdx.x - gF0) * 1024 + threadIdx.x;
        #pragma unroll
        for (int j = 0; j < 4; ++j) {
            int e = base + j * 256;
            if (e < E1) {
                int d = dst1[e];
                if (d < BS) ssrc[rowptr[N + d] + rank[E0 + e]] = src1[e];
            }
        }
    }
}

// ---- agg0 over live nodes only (livelist-driven) ----------------------------
__global__ __launch_bounds__(256) void k_aggL(const unsigned* __restrict__ xl,
                                              const int* __restrict__ rowptr,
                                              const int* __restrict__ cnt,
                                              const int* __restrict__ ssrc,
                                              const float* __restrict__ att,
                                              const float* __restrict__ bias,
                                              float* __restrict__ out,
                                              const int* __restrict__ livelist,
                                              const int* __restrict__ nLive) {
    int li = blockIdx.x * 4 + (threadIdx.x >> 6);
    if (li >= *nLive) return;
    int node = __builtin_amdgcn_readfirstlane(livelist[li]);
    int lane = threadIdx.x & 63;
    float2 attv = *(const float2*)&att[lane * 2];
    float2 xd = bf2f(xl[(size_t)node * 64 + lane]);
    int rs  = rowptr[node];
    int deg = cnt[node];

    float m = -3.4e38f, den = 0.f, accx = 0.f, accy = 0.f;
    int sA = (deg > 0) ? ssrc[rs] : 0;
    int sB = (deg > 1) ? ssrc[rs + 1] : 0;
    unsigned uA = xl[(size_t)sA * 64 + lane];
    unsigned uB = xl[(size_t)sB * 64 + lane];

    int k = 0;
    for (; k + 1 < deg; k += 2) {
        int sC = (k + 2 < deg) ? ssrc[rs + k + 2] : 0;
        int sD = (k + 3 < deg) ? ssrc[rs + k + 3] : 0;
        unsigned uC = xl[(size_t)sC * 64 + lane];
        unsigned uD = xl[(size_t)sD * 64 + lane];
        float2 vA = bf2f(uA), vB = bf2f(uB);

        float tx = xd.x + vA.x, ty = xd.y + vA.y;
        tx = tx > 0.f ? tx : 0.2f * tx;
        ty = ty > 0.f ? ty : 0.2f * ty;
        float l0 = tx * attv.x + ty * attv.y;
        tx = xd.x + vB.x; ty = xd.y + vB.y;
        tx = tx > 0.f ? tx : 0.2f * tx;
        ty = ty > 0.f ? ty : 0.2f * ty;
        float l1 = tx * attv.x + ty * attv.y;
        #pragma unroll
        for (int o = 8; o; o >>= 1) {
            l0 += __shfl_xor(l0, o, 64);
            l1 += __shfl_xor(l1, o, 64);
        }
        float mn = fmaxf(fmaxf(m, l0), l1);
        float corr = __expf(m - mn);
        float w0 = __expf(l0 - mn);
        float w1 = __expf(l1 - mn);
        den  = den  * corr + w0 + w1;
        accx = accx * corr + w0 * vA.x + w1 * vB.x;
        accy = accy * corr + w0 * vA.y + w1 * vB.y;
        m = mn;
        sA = sC; sB = sD; uA = uC; uB = uD;
    }
    if (k < deg) {
        float2 vA = bf2f(uA);
        float tx = xd.x + vA.x, ty = xd.y + vA.y;
        tx = tx > 0.f ? tx : 0.2f * tx;
        ty = ty > 0.f ? ty : 0.2f * ty;
        float l0 = tx * attv.x + ty * attv.y;
        #pragma unroll
        for (int o = 8; o; o >>= 1) l0 += __shfl_xor(l0, o, 64);
        float mn = fmaxf(m, l0);
        float corr = __expf(m - mn);
        float w0 = __expf(l0 - mn);
        den  = den  * corr + w0;
        accx = accx * corr + w0 * vA.x;
        accy = accy * corr + w0 * vA.y;
    }

    float inv = (deg > 0) ? 1.f / den : 0.f;
    float2 o2;
    o2.x = accx * inv + bias[lane * 2];
    o2.y = accy * inv + bias[lane * 2 + 1];
    *(float2*)&out[(size_t)node * DD + lane * 2] = o2;
}

// ---- lin1 over livelist rows only (gelu on input) ---------------------------
__global__ __launch_bounds__(256) void k_linC(const float* __restrict__ x,
                                              const float* __restrict__ w,
                                              const float* __restrict__ b,
                                              unsigned* __restrict__ y,
                                              const int* __restrict__ livelist,
                                              const int* __restrict__ nLive) {
    __shared__ float  xs[64][DD];
    __shared__ float4 wb[32][32];
    int nL = *nLive;
    int lbase = blockIdx.x * 64;
    if (lbase >= nL) return;

    for (int i = threadIdx.x; i < 64 * 32; i += 256) {
        int li = lbase + (i >> 5);
        float4 v = make_float4(0.f, 0.f, 0.f, 0.f);
        if (li < nL) {
            int r = livelist[li];
            v = ((const float4*)x)[(size_t)r * 32 + (i & 31)];
            v.x = 0.5f * v.x * (1.f + erff(v.x * 0.70710678f));
            v.y = 0.5f * v.y * (1.f + erff(v.y * 0.70710678f));
            v.z = 0.5f * v.z * (1.f + erff(v.z * 0.70710678f));
            v.w = 0.5f * v.w * (1.f + erff(v.w * 0.70710678f));
        }
        *(float4*)&xs[i >> 5][(i & 31) * 4] = v;
    }
    int g  = threadIdx.x >> 5;
    int cg = threadIdx.x & 31;
    float4 bb = ((const float4*)b)[cg];
    float4 acc[8];
    #pragma unroll
    for (int r = 0; r < 8; ++r) acc[r] = bb;
    const float4* wv = (const float4*)w;
    for (int kc = 0; kc < DD; kc += 32) {
        __syncthreads();
        for (int i = threadIdx.x; i < 32 * 32; i += 256)
            wb[i >> 5][i & 31] = wv[(size_t)(kc + (i >> 5)) * 32 + (i & 31)];
        __syncthreads();
        #pragma unroll 8
        for (int kk = 0; kk < 32; ++kk) {
            float4 wk = wb[kk][cg];
            #pragma unroll
            for (int r = 0; r < 8; ++r) {
                float xv = xs[g * 8 + r][kc + kk];
                acc[r].x += xv * wk.x; acc[r].y += xv * wk.y;
                acc[r].z += xv * wk.z; acc[r].w += xv * wk.w;
            }
        }
    }
    #pragma unroll
    for (int r = 0; r < 8; ++r) {
        int li = lbase + g * 8 + r;
        if (li < nL) {
            int row = livelist[li];
            uint2 p;
            p.x = bf16rne(acc[r].x) | (bf16rne(acc[r].y) << 16);
            p.y = bf16rne(acc[r].z) | (bf16rne(acc[r].w) << 16);
            ((uint2*)y)[(size_t)row * 32 + cg] = p;
        }
    }
}

// ---- agg1 (nodes [0,BS)) fused with linear+LayerNorm head -------------------
__global__ __launch_bounds__(256) void k_agg1head(
        const unsigned* __restrict__ xl,
        const int* __restrict__ rowptr, const int* __restrict__ cnt,
        const int* __restrict__ ssrc,
        const float* __restrict__ att, const float* __restrict__ bias,
        const float* __restrict__ wout, const float* __restrict__ bout,
        const float* __restrict__ gamma, const float* __restrict__ beta,
        float* __restrict__ yout, int N, int BS) {
    __shared__ float xrow[4][DD];
    int wid  = threadIdx.x >> 6;
    int lane = threadIdx.x & 63;
    int node = blockIdx.x * 4 + wid;
    if (node >= BS) return;
    float2 attv = *(const float2*)&att[lane * 2];
    float2 xd = bf2f(xl[(size_t)node * 64 + lane]);
    int key = N + node;
    int rs  = rowptr[key];
    int deg = cnt[key];

    float m = -3.4e38f, den = 0.f, accx = 0.f, accy = 0.f;
    int sA = (deg > 0) ? ssrc[rs] : 0;
    int sB = (deg > 1) ? ssrc[rs + 1] : 0;
    unsigned uA = xl[(size_t)sA * 64 + lane];
    unsigned uB = xl[(size_t)sB * 64 + lane];

    int k = 0;
    for (; k + 1 < deg; k += 2) {
        int sC = (k + 2 < deg) ? ssrc[rs + k + 2] : 0;
        int sD = (k + 3 < deg) ? ssrc[rs + k + 3] : 0;
        unsigned uC = xl[(size_t)sC * 64 + lane];
        unsigned uD = xl[(size_t)sD * 64 + lane];
        float2 vA = bf2f(uA), vB = bf2f(uB);
        float tx = xd.x + vA.x, ty = xd.y + vA.y;
        tx = tx > 0.f ? tx : 0.2f * tx;
        ty = ty > 0.f ? ty : 0.2f * ty;
        float l0 = tx * attv.x + ty * attv.y;
        tx = xd.x + vB.x; ty = xd.y + vB.y;
        tx = tx > 0.f ? tx : 0.2f * tx;
        ty = ty > 0.f ? ty : 0.2f * ty;
        float l1 = tx * attv.x + ty * attv.y;
        #pragma unroll
        for (int o = 8; o; o >>= 1) {
            l0 += __shfl_xor(l0, o, 64);
            l1 += __shfl_xor(l1, o, 64);
        }
        float mn = fmaxf(fmaxf(m, l0), l1);
        float corr = __expf(m - mn);
        float w0 = __expf(l0 - mn);
        float w1 = __expf(l1 - mn);
        den  = den  * corr + w0 + w1;
        accx = accx * corr + w0 * vA.x + w1 * vB.x;
        accy = accy * corr + w0 * vA.y + w1 * vB.y;
        m = mn;
        sA = sC; sB = sD; uA = uC; uB = uD;
    }
    if (k < deg) {
        float2 vA = bf2f(uA);
        float tx = xd.x + vA.x, ty = xd.y + vA.y;
        tx = tx > 0.f ? tx : 0.2f * tx;
        ty = ty > 0.f ? ty : 0.2f * ty;
        float l0 = tx * attv.x + ty * attv.y;
        #pragma unroll
        for (int o = 8; o; o >>= 1) l0 += __shfl_xor(l0, o, 64);
        float mn = fmaxf(m, l0);
        float corr = __expf(m - mn);
        float w0 = __expf(l0 - mn);
        den  = den  * corr + w0;
        accx = accx * corr + w0 * vA.x;
        accy = accy * corr + w0 * vA.y;
    }

    float inv = (deg > 0) ? 1.f / den : 0.f;
    float2 o2;
    o2.x = accx * inv + bias[lane * 2];
    o2.y = accy * inv + bias[lane * 2 + 1];

    // ---- head: y = LN(o2row @ wout + bout) * gamma + beta ----
    xrow[wid][lane * 2]     = o2.x;
    xrow[wid][lane * 2 + 1] = o2.y;
    float2 acc2 = *(const float2*)&bout[lane * 2];
    #pragma unroll 4
    for (int kk = 0; kk < DD; ++kk) {
        float xv = xrow[wid][kk];
        float2 wv2 = *(const float2*)&wout[(size_t)kk * DD + lane * 2];
        acc2.x += xv * wv2.x;
        acc2.y += xv * wv2.y;
    }
    float s = acc2.x + acc2.y;
    #pragma unroll
    for (int o = 32; o; o >>= 1) s += __shfl_xor(s, o, 64);
    float mean = s * (1.f / 128.f);
    float dx = acc2.x - mean, dy = acc2.y - mean;
    float s2 = dx * dx + dy * dy;
    #pragma unroll
    for (int o = 32; o; o >>= 1) s2 += __shfl_xor(s2, o, 64);
    float rstd = rsqrtf(s2 * (1.f / 128.f) + 1e-12f);
    float2 g2 = *(const float2*)&gamma[lane * 2];
    float2 b2 = *(const float2*)&beta[lane * 2];
    float2 yo;
    yo.x = dx * rstd * g2.x + b2.x;
    yo.y = dy * rstd * g2.y + b2.y;
    *(float2*)&yout[(size_t)node * DD + lane * 2] = yo;
}

extern "C" void kernel_launch(void* const* d_in, const int* in_sizes, int n_in,
                              void* d_out, int out_size, void* d_ws, size_t ws_size,
                              hipStream_t stream) {
    const float* embs  = (const float*)d_in[0];
    const float* w0    = (const float*)d_in[1];
    const float* b0    = (const float*)d_in[2];
    const float* att0  = (const float*)d_in[3];
    const float* bias0 = (const float*)d_in[4];
    const float* w1    = (const float*)d_in[5];
    const float* b1    = (const float*)d_in[6];
    const float* att1  = (const float*)d_in[7];
    const float* bias1 = (const float*)d_in[8];
    const float* wout  = (const float*)d_in[9];
    const float* bout  = (const float*)d_in[10];
    const float* gamma = (const float*)d_in[11];
    const float* beta  = (const float*)d_in[12];
    const int* ei0 = (const int*)d_in[13];
    const int* ei1 = (const int*)d_in[14];

    int N  = in_sizes[0] / DD;
    int E0 = in_sizes[13] / 2;
    int E1 = in_sizes[14] / 2;
    int BS = out_size / DD;
    int n2 = N + BS;

    // ---- workspace carve-up ----
    unsigned* xl   = (unsigned*)d_ws;                      // N*64 (bf16 pairs)
    float* out     = (float*)(xl + (size_t)N * 64);        // N*128 f32
    int* ssrc      = (int*)(out + (size_t)N * DD);         // E0+E1
    int* rank      = ssrc + (E0 + E1);                     // E0+E1
    int* cnt       = rank + (E0 + E1);                     // n2   (memset)
    int* mask      = cnt + n2;                             // N    (memset, adjacent)
    int* rowptr    = mask + N;                             // n2
    int* ex        = rowptr + n2;                          // n2
    int* bsum      = ex + n2;                              // 256
    int* mex       = bsum + 256;                           // N
    int* mbsum     = mex + N;                              // 256
    int* livelist  = mbsum + 256;                          // N
    int* nLive     = livelist + N;                         // 1

    int gH0   = (E0 + 1023) / 1024;
    int gH1   = (E1 + 1023) / 1024;
    int gLin  = (N + 63) / 64;
    int gS    = (n2 + 255) / 256;     // 200
    int gMs   = (N + 255) / 256;      // 196
    int gAgg  = (N + 3) / 4;

    // 1. zero cnt + mask (contiguous)
    hipMemsetAsync(cnt, 0, (size_t)(n2 + N) * sizeof(int), stream);
    // 2. mark live nodes from conv1 edges
    k_mark<<<gH1, 256, 0, stream>>>(ei1, ei1 + E1, E1, BS, mask);
    // 3. compact livelist
    k_scanA<<<gMs, 256, 0, stream>>>(mask, N, mex, mbsum);
    k_scanB<<<1, 256, 0, stream>>>(mbsum, gMs);
    k_mscanC<<<gMs, 256, 0, stream>>>(mask, mex, mbsum, livelist, nLive, N);
    // 4. F1: filtered hist (both convs) || linear0
    k_histlin<<<gH0 + gH1 + gLin, 256, 0, stream>>>(
        embs, w0, b0, xl, N, gH0, gH1,
        ei0 + E0, E0, ei1 + E1, E1, BS, mask, cnt, rank, N);
    // 5. CSR scan
    k_scanA<<<gS, 256, 0, stream>>>(cnt, n2, ex, bsum);
    k_scanB<<<1, 256, 0, stream>>>(bsum, gS);
    k_scanC<<<gS, 256, 0, stream>>>(ex, bsum, rowptr, n2);
    // 6. F2: fill both convs' live edges
    k_fill<<<gH0 + gH1, 256, 0, stream>>>(ei0, ei0 + E0, E0, ei1, ei1 + E1, E1,
                                          BS, gH0, mask, rowptr, rank, ssrc, N);
    // 7. agg0 over live nodes only
    k_aggL<<<gAgg, 256, 0, stream>>>(xl, rowptr, cnt, ssrc, att0, bias0, out,
                                     livelist, nLive);
    // 8. lin1 over live rows only (gelu)
    k_linC<<<gLin, 256, 0, stream>>>(out, w1, b1, xl, livelist, nLive);
    // 9. agg1 (dst<BS) + head
    k_agg1head<<<(BS + 3) / 4, 256, 0, stream>>>(
        xl, rowptr, cnt, ssrc, att1, bias1,
        wout, bout, gamma, beta, (float*)d_out, N, BS);
}

// Round 9
// 118.167 us; speedup vs baseline: 9.1460x; 1.1126x over previous
//
#include <hip/hip_runtime.h>
#include <math.h>

#define DD 128

__device__ __forceinline__ unsigned bf16rne(float f) {
    unsigned u = __float_as_uint(f);
    return (u + 0x7FFFu + ((u >> 16) & 1u)) >> 16;
}
__device__ __forceinline__ float2 bf2f(unsigned u) {
    float2 r;
    r.x = __uint_as_float(u << 16);
    r.y = __uint_as_float(u & 0xFFFF0000u);
    return r;
}

// ---- mark live nodes into a BITMASK (6.25 KB -> L1-resident) ---------------
__global__ __launch_bounds__(256) void k_mark(const int* __restrict__ src1,
                                              const int* __restrict__ dst1,
                                              int E1, int BS,
                                              unsigned* __restrict__ mb) {
    int base = blockIdx.x * 1024 + threadIdx.x;
    #pragma unroll
    for (int j = 0; j < 4; ++j) {
        int e = base + j * 256;
        if (e < E1) {
            int d = dst1[e];
            if (d < BS) {
                int s = src1[e];
                atomicOr(&mb[s >> 5], 1u << (s & 31));
            }
        }
    }
    int g = blockIdx.x * 256 + threadIdx.x;
    if (g < BS) atomicOr(&mb[g >> 5], 1u << (g & 31));
}

// ---- F1: linear0 (32-row tiles) || filtered hist (both convs) || mscanA ----
__global__ __launch_bounds__(256) void k_histlin(
        const float* __restrict__ x, const float* __restrict__ w,
        const float* __restrict__ b, unsigned* __restrict__ y, int nrows,
        int gLin, int gH0, int gH1,
        const int* __restrict__ dst0, int E0,
        const int* __restrict__ dst1, int E1, int BS,
        const unsigned* __restrict__ mb, int* __restrict__ cnt,
        int* __restrict__ rank, int N,
        int W, int* __restrict__ mex, int* __restrict__ mbsum) {
    __shared__ float  xs[32][DD];     // 16 KB
    __shared__ float4 wb[32][32];     // 16 KB

    if (blockIdx.x >= gLin) {
        int role = blockIdx.x - gLin;
        if (role < gH0) {                       // hist conv0 (live dst only)
            int base = role * 1024 + threadIdx.x;
            #pragma unroll
            for (int j = 0; j < 4; ++j) {
                int e = base + j * 256;
                if (e < E0) {
                    int d = dst0[e];
                    if ((mb[d >> 5] >> (d & 31)) & 1u)
                        rank[e] = atomicAdd(&cnt[d], 1);
                }
            }
        } else if (role < gH0 + gH1) {          // hist conv1 (dst < BS)
            int base = (role - gH0) * 1024 + threadIdx.x;
            #pragma unroll
            for (int j = 0; j < 4; ++j) {
                int e = base + j * 256;
                if (e < E1) {
                    int d = dst1[e];
                    if (d < BS) rank[E0 + e] = atomicAdd(&cnt[N + d], 1);
                }
            }
        } else {                                // mscanA over mask words
            __shared__ int s[256];
            int idx = (role - gH0 - gH1) * 256 + threadIdx.x;
            int v = (idx < W) ? __popc(mb[idx]) : 0;
            s[threadIdx.x] = v;
            __syncthreads();
            for (int o = 1; o < 256; o <<= 1) {
                int t = (threadIdx.x >= o) ? s[threadIdx.x - o] : 0;
                __syncthreads();
                s[threadIdx.x] += t;
                __syncthreads();
            }
            if (idx < W) mex[idx] = s[threadIdx.x] - v;
            if (threadIdx.x == 255) mbsum[role - gH0 - gH1] = s[255];
        }
        return;
    }

    // ---- linear: 32 rows x 128 cols ----
    int rbase = blockIdx.x * 32;
    for (int i = threadIdx.x; i < 32 * 32; i += 256) {
        int r = rbase + (i >> 5);
        float4 v = make_float4(0.f, 0.f, 0.f, 0.f);
        if (r < nrows) v = ((const float4*)x)[(size_t)r * 32 + (i & 31)];
        *(float4*)&xs[i >> 5][(i & 31) * 4] = v;
    }
    int g  = threadIdx.x >> 5;
    int cg = threadIdx.x & 31;
    float4 bb = ((const float4*)b)[cg];
    float4 acc[4];
    #pragma unroll
    for (int r = 0; r < 4; ++r) acc[r] = bb;
    const float4* wv = (const float4*)w;
    for (int kc = 0; kc < DD; kc += 32) {
        __syncthreads();
        for (int i = threadIdx.x; i < 32 * 32; i += 256)
            wb[i >> 5][i & 31] = wv[(size_t)(kc + (i >> 5)) * 32 + (i & 31)];
        __syncthreads();
        #pragma unroll 8
        for (int kk = 0; kk < 32; ++kk) {
            float4 wk = wb[kk][cg];
            #pragma unroll
            for (int r = 0; r < 4; ++r) {
                float xv = xs[g * 4 + r][kc + kk];
                acc[r].x += xv * wk.x; acc[r].y += xv * wk.y;
                acc[r].z += xv * wk.z; acc[r].w += xv * wk.w;
            }
        }
    }
    #pragma unroll
    for (int r = 0; r < 4; ++r) {
        int row = rbase + g * 4 + r;
        if (row < nrows) {
            uint2 p;
            p.x = bf16rne(acc[r].x) | (bf16rne(acc[r].y) << 16);
            p.y = bf16rne(acc[r].z) | (bf16rne(acc[r].w) << 16);
            ((uint2*)y)[(size_t)row * 32 + cg] = p;
        }
    }
}

// ---- K3: scanA over cnt (blocks 0..gS-1) + tiny serial mscanB (block gS) ---
__global__ __launch_bounds__(256) void k_scanA2(const int* __restrict__ cnt, int n,
                                                int* __restrict__ ex,
                                                int* __restrict__ bsum, int gS,
                                                int* __restrict__ mbsum, int nMs) {
    if (blockIdx.x == gS) {
        if (threadIdx.x == 0) {
            int run = 0;
            for (int i = 0; i < nMs; ++i) { int t = mbsum[i]; mbsum[i] = run; run += t; }
        }
        return;
    }
    __shared__ int s[256];
    int idx = blockIdx.x * 256 + threadIdx.x;
    int v = (idx < n) ? cnt[idx] : 0;
    s[threadIdx.x] = v;
    __syncthreads();
    for (int o = 1; o < 256; o <<= 1) {
        int t = (threadIdx.x >= o) ? s[threadIdx.x - o] : 0;
        __syncthreads();
        s[threadIdx.x] += t;
        __syncthreads();
    }
    if (idx < n) ex[idx] = s[threadIdx.x] - v;
    if (threadIdx.x == 255) bsum[blockIdx.x] = s[255];
}

// ---- K4: mscanC (livelist, blocks 0..gMs-1) + scanB over bsum (block gMs) --
__global__ __launch_bounds__(256) void k_mscanC2(const unsigned* __restrict__ mb,
                                                 int W,
                                                 const int* __restrict__ mex,
                                                 const int* __restrict__ mbsum,
                                                 int* __restrict__ livelist,
                                                 int* __restrict__ nLive,
                                                 int gMs,
                                                 int* __restrict__ bsum, int nb) {
    if (blockIdx.x == gMs) {
        __shared__ int s[256];
        int v = (threadIdx.x < nb) ? bsum[threadIdx.x] : 0;
        s[threadIdx.x] = v;
        __syncthreads();
        for (int o = 1; o < 256; o <<= 1) {
            int t = (threadIdx.x >= o) ? s[threadIdx.x - o] : 0;
            __syncthreads();
            s[threadIdx.x] += t;
            __syncthreads();
        }
        if (threadIdx.x < nb) bsum[threadIdx.x] = s[threadIdx.x] - v;
        return;
    }
    int idx = blockIdx.x * 256 + threadIdx.x;
    if (idx < W) {
        unsigned word = mb[idx];
        int base = mex[idx] + mbsum[blockIdx.x];
        unsigned wt = word;
        while (wt) {
            int bit = __ffs(wt) - 1;
            livelist[base + __popc(word & ((1u << bit) - 1u))] = idx * 32 + bit;
            wt &= wt - 1;
        }
        if (idx == W - 1) *nLive = base + __popc(word);
    }
}

__global__ __launch_bounds__(256) void k_scanC(const int* __restrict__ ex,
                                               const int* __restrict__ bsum,
                                               int* __restrict__ rowptr, int n) {
    int idx = blockIdx.x * 256 + threadIdx.x;
    if (idx < n) rowptr[idx] = ex[idx] + bsum[blockIdx.x];
}

// ---- F2: CSR fill for live conv0 edges + conv1 dst<BS edges ----------------
__global__ __launch_bounds__(256) void k_fill(const int* __restrict__ src0,
                                              const int* __restrict__ dst0, int E0,
                                              const int* __restrict__ src1,
                                              const int* __restrict__ dst1, int E1,
                                              int BS, int gF0,
                                              const unsigned* __restrict__ mb,
                                              const int* __restrict__ rowptr,
                                              const int* __restrict__ rank,
                                              int* __restrict__ ssrc, int N) {
    if (blockIdx.x < gF0) {
        int base = blockIdx.x * 1024 + threadIdx.x;
        #pragma unroll
        for (int j = 0; j < 4; ++j) {
            int e = base + j * 256;
            if (e < E0) {
                int d = dst0[e];
                if ((mb[d >> 5] >> (d & 31)) & 1u)
                    ssrc[rowptr[d] + rank[e]] = src0[e];
            }
        }
    } else {
        int base = (blockIdx.x - gF0) * 1024 + threadIdx.x;
        #pragma unroll
        for (int j = 0; j < 4; ++j) {
            int e = base + j * 256;
            if (e < E1) {
                int d = dst1[e];
                if (d < BS) ssrc[rowptr[N + d] + rank[E0 + e]] = src1[e];
            }
        }
    }
}

// ---- agg0 over live nodes only (livelist-driven) ----------------------------
__global__ __launch_bounds__(256) void k_aggL(const unsigned* __restrict__ xl,
                                              const int* __restrict__ rowptr,
                                              const int* __restrict__ cnt,
                                              const int* __restrict__ ssrc,
                                              const float* __restrict__ att,
                                              const float* __restrict__ bias,
                                              float* __restrict__ out,
                                              const int* __restrict__ livelist,
                                              const int* __restrict__ nLive) {
    int li = blockIdx.x * 4 + (threadIdx.x >> 6);
    if (li >= *nLive) return;
    int node = __builtin_amdgcn_readfirstlane(livelist[li]);
    int lane = threadIdx.x & 63;
    float2 attv = *(const float2*)&att[lane * 2];
    float2 xd = bf2f(xl[(size_t)node * 64 + lane]);
    int rs  = rowptr[node];
    int deg = cnt[node];

    float m = -3.4e38f, den = 0.f, accx = 0.f, accy = 0.f;
    int sA = (deg > 0) ? ssrc[rs] : 0;
    int sB = (deg > 1) ? ssrc[rs + 1] : 0;
    unsigned uA = xl[(size_t)sA * 64 + lane];
    unsigned uB = xl[(size_t)sB * 64 + lane];

    int k = 0;
    for (; k + 1 < deg; k += 2) {
        int sC = (k + 2 < deg) ? ssrc[rs + k + 2] : 0;
        int sD = (k + 3 < deg) ? ssrc[rs + k + 3] : 0;
        unsigned uC = xl[(size_t)sC * 64 + lane];
        unsigned uD = xl[(size_t)sD * 64 + lane];
        float2 vA = bf2f(uA), vB = bf2f(uB);

        float tx = xd.x + vA.x, ty = xd.y + vA.y;
        tx = tx > 0.f ? tx : 0.2f * tx;
        ty = ty > 0.f ? ty : 0.2f * ty;
        float l0 = tx * attv.x + ty * attv.y;
        tx = xd.x + vB.x; ty = xd.y + vB.y;
        tx = tx > 0.f ? tx : 0.2f * tx;
        ty = ty > 0.f ? ty : 0.2f * ty;
        float l1 = tx * attv.x + ty * attv.y;
        #pragma unroll
        for (int o = 8; o; o >>= 1) {
            l0 += __shfl_xor(l0, o, 64);
            l1 += __shfl_xor(l1, o, 64);
        }
        float mn = fmaxf(fmaxf(m, l0), l1);
        float corr = __expf(m - mn);
        float w0 = __expf(l0 - mn);
        float w1 = __expf(l1 - mn);
        den  = den  * corr + w0 + w1;
        accx = accx * corr + w0 * vA.x + w1 * vB.x;
        accy = accy * corr + w0 * vA.y + w1 * vB.y;
        m = mn;
        sA = sC; sB = sD; uA = uC; uB = uD;
    }
    if (k < deg) {
        float2 vA = bf2f(uA);
        float tx = xd.x + vA.x, ty = xd.y + vA.y;
        tx = tx > 0.f ? tx : 0.2f * tx;
        ty = ty > 0.f ? ty : 0.2f * ty;
        float l0 = tx * attv.x + ty * attv.y;
        #pragma unroll
        for (int o = 8; o; o >>= 1) l0 += __shfl_xor(l0, o, 64);
        float mn = fmaxf(m, l0);
        float corr = __expf(m - mn);
        float w0 = __expf(l0 - mn);
        den  = den  * corr + w0;
        accx = accx * corr + w0 * vA.x;
        accy = accy * corr + w0 * vA.y;
    }

    float inv = (deg > 0) ? 1.f / den : 0.f;
    float2 o2;
    o2.x = accx * inv + bias[lane * 2];
    o2.y = accy * inv + bias[lane * 2 + 1];
    *(float2*)&out[(size_t)node * DD + lane * 2] = o2;
}

// ---- lin1 over livelist rows only (gelu on input, 32-row tiles) -------------
__global__ __launch_bounds__(256) void k_linC(const float* __restrict__ x,
                                              const float* __restrict__ w,
                                              const float* __restrict__ b,
                                              unsigned* __restrict__ y,
                                              const int* __restrict__ livelist,
                                              const int* __restrict__ nLive) {
    __shared__ float  xs[32][DD];
    __shared__ float4 wb[32][32];
    int nL = *nLive;
    int lbase = blockIdx.x * 32;
    if (lbase >= nL) return;

    for (int i = threadIdx.x; i < 32 * 32; i += 256) {
        int li = lbase + (i >> 5);
        float4 v = make_float4(0.f, 0.f, 0.f, 0.f);
        if (li < nL) {
            int r = livelist[li];
            v = ((const float4*)x)[(size_t)r * 32 + (i & 31)];
            v.x = 0.5f * v.x * (1.f + erff(v.x * 0.70710678f));
            v.y = 0.5f * v.y * (1.f + erff(v.y * 0.70710678f));
            v.z = 0.5f * v.z * (1.f + erff(v.z * 0.70710678f));
            v.w = 0.5f * v.w * (1.f + erff(v.w * 0.70710678f));
        }
        *(float4*)&xs[i >> 5][(i & 31) * 4] = v;
    }
    int g  = threadIdx.x >> 5;
    int cg = threadIdx.x & 31;
    float4 bb = ((const float4*)b)[cg];
    float4 acc[4];
    #pragma unroll
    for (int r = 0; r < 4; ++r) acc[r] = bb;
    const float4* wv = (const float4*)w;
    for (int kc = 0; kc < DD; kc += 32) {
        __syncthreads();
        for (int i = threadIdx.x; i < 32 * 32; i += 256)
            wb[i >> 5][i & 31] = wv[(size_t)(kc + (i >> 5)) * 32 + (i & 31)];
        __syncthreads();
        #pragma unroll 8
        for (int kk = 0; kk < 32; ++kk) {
            float4 wk = wb[kk][cg];
            #pragma unroll
            for (int r = 0; r < 4; ++r) {
                float xv = xs[g * 4 + r][kc + kk];
                acc[r].x += xv * wk.x; acc[r].y += xv * wk.y;
                acc[r].z += xv * wk.z; acc[r].w += xv * wk.w;
            }
        }
    }
    #pragma unroll
    for (int r = 0; r < 4; ++r) {
        int li = lbase + g * 4 + r;
        if (li < nL) {
            int row = livelist[li];
            uint2 p;
            p.x = bf16rne(acc[r].x) | (bf16rne(acc[r].y) << 16);
            p.y = bf16rne(acc[r].z) | (bf16rne(acc[r].w) << 16);
            ((uint2*)y)[(size_t)row * 32 + cg] = p;
        }
    }
}

// ---- agg1 (nodes [0,BS)) fused with linear+LayerNorm head -------------------
__global__ __launch_bounds__(256) void k_agg1head(
        const unsigned* __restrict__ xl,
        const int* __restrict__ rowptr, const int* __restrict__ cnt,
        const int* __restrict__ ssrc,
        const float* __restrict__ att, const float* __restrict__ bias,
        const float* __restrict__ wout, const float* __restrict__ bout,
        const float* __restrict__ gamma, const float* __restrict__ beta,
        float* __restrict__ yout, int N, int BS) {
    __shared__ float xrow[4][DD];
    int wid  = threadIdx.x >> 6;
    int lane = threadIdx.x & 63;
    int node = blockIdx.x * 4 + wid;
    if (node >= BS) return;
    float2 attv = *(const float2*)&att[lane * 2];
    float2 xd = bf2f(xl[(size_t)node * 64 + lane]);
    int key = N + node;
    int rs  = rowptr[key];
    int deg = cnt[key];

    float m = -3.4e38f, den = 0.f, accx = 0.f, accy = 0.f;
    int sA = (deg > 0) ? ssrc[rs] : 0;
    int sB = (deg > 1) ? ssrc[rs + 1] : 0;
    unsigned uA = xl[(size_t)sA * 64 + lane];
    unsigned uB = xl[(size_t)sB * 64 + lane];

    int k = 0;
    for (; k + 1 < deg; k += 2) {
        int sC = (k + 2 < deg) ? ssrc[rs + k + 2] : 0;
        int sD = (k + 3 < deg) ? ssrc[rs + k + 3] : 0;
        unsigned uC = xl[(size_t)sC * 64 + lane];
        unsigned uD = xl[(size_t)sD * 64 + lane];
        float2 vA = bf2f(uA), vB = bf2f(uB);
        float tx = xd.x + vA.x, ty = xd.y + vA.y;
        tx = tx > 0.f ? tx : 0.2f * tx;
        ty = ty > 0.f ? ty : 0.2f * ty;
        float l0 = tx * attv.x + ty * attv.y;
        tx = xd.x + vB.x; ty = xd.y + vB.y;
        tx = tx > 0.f ? tx : 0.2f * tx;
        ty = ty > 0.f ? ty : 0.2f * ty;
        float l1 = tx * attv.x + ty * attv.y;
        #pragma unroll
        for (int o = 8; o; o >>= 1) {
            l0 += __shfl_xor(l0, o, 64);
            l1 += __shfl_xor(l1, o, 64);
        }
        float mn = fmaxf(fmaxf(m, l0), l1);
        float corr = __expf(m - mn);
        float w0 = __expf(l0 - mn);
        float w1 = __expf(l1 - mn);
        den  = den  * corr + w0 + w1;
        accx = accx * corr + w0 * vA.x + w1 * vB.x;
        accy = accy * corr + w0 * vA.y + w1 * vB.y;
        m = mn;
        sA = sC; sB = sD; uA = uC; uB = uD;
    }
    if (k < deg) {
        float2 vA = bf2f(uA);
        float tx = xd.x + vA.x, ty = xd.y + vA.y;
        tx = tx > 0.f ? tx : 0.2f * tx;
        ty = ty > 0.f ? ty : 0.2f * ty;
        float l0 = tx * attv.x + ty * attv.y;
        #pragma unroll
        for (int o = 8; o; o >>= 1) l0 += __shfl_xor(l0, o, 64);
        float mn = fmaxf(m, l0);
        float corr = __expf(m - mn);
        float w0 = __expf(l0 - mn);
        den  = den  * corr + w0;
        accx = accx * corr + w0 * vA.x;
        accy = accy * corr + w0 * vA.y;
    }

    float inv = (deg > 0) ? 1.f / den : 0.f;
    float2 o2;
    o2.x = accx * inv + bias[lane * 2];
    o2.y = accy * inv + bias[lane * 2 + 1];

    xrow[wid][lane * 2]     = o2.x;
    xrow[wid][lane * 2 + 1] = o2.y;
    float2 acc2 = *(const float2*)&bout[lane * 2];
    #pragma unroll 4
    for (int kk = 0; kk < DD; ++kk) {
        float xv = xrow[wid][kk];
        float2 wv2 = *(const float2*)&wout[(size_t)kk * DD + lane * 2];
        acc2.x += xv * wv2.x;
        acc2.y += xv * wv2.y;
    }
    float s = acc2.x + acc2.y;
    #pragma unroll
    for (int o = 32; o; o >>= 1) s += __shfl_xor(s, o, 64);
    float mean = s * (1.f / 128.f);
    float dx = acc2.x - mean, dy = acc2.y - mean;
    float s2 = dx * dx + dy * dy;
    #pragma unroll
    for (int o = 32; o; o >>= 1) s2 += __shfl_xor(s2, o, 64);
    float rstd = rsqrtf(s2 * (1.f / 128.f) + 1e-12f);
    float2 g2 = *(const float2*)&gamma[lane * 2];
    float2 b2 = *(const float2*)&beta[lane * 2];
    float2 yo;
    yo.x = dx * rstd * g2.x + b2.x;
    yo.y = dy * rstd * g2.y + b2.y;
    *(float2*)&yout[(size_t)node * DD + lane * 2] = yo;
}

extern "C" void kernel_launch(void* const* d_in, const int* in_sizes, int n_in,
                              void* d_out, int out_size, void* d_ws, size_t ws_size,
                              hipStream_t stream) {
    const float* embs  = (const float*)d_in[0];
    const float* w0    = (const float*)d_in[1];
    const float* b0    = (const float*)d_in[2];
    const float* att0  = (const float*)d_in[3];
    const float* bias0 = (const float*)d_in[4];
    const float* w1    = (const float*)d_in[5];
    const float* b1    = (const float*)d_in[6];
    const float* att1  = (const float*)d_in[7];
    const float* bias1 = (const float*)d_in[8];
    const float* wout  = (const float*)d_in[9];
    const float* bout  = (const float*)d_in[10];
    const float* gamma = (const float*)d_in[11];
    const float* beta  = (const float*)d_in[12];
    const int* ei0 = (const int*)d_in[13];
    const int* ei1 = (const int*)d_in[14];

    int N  = in_sizes[0] / DD;
    int E0 = in_sizes[13] / 2;
    int E1 = in_sizes[14] / 2;
    int BS = out_size / DD;
    int n2 = N + BS;
    int W  = (N + 31) / 32;

    // ---- workspace carve-up ----
    unsigned* xl   = (unsigned*)d_ws;                      // N*64 (bf16 pairs)
    float* out     = (float*)(xl + (size_t)N * 64);        // N*128 f32
    int* ssrc      = (int*)(out + (size_t)N * DD);         // E0+E1
    int* rank      = ssrc + (E0 + E1);                     // E0+E1
    int* cnt       = rank + (E0 + E1);                     // n2   (memset)
    unsigned* mb   = (unsigned*)(cnt + n2);                // W+32 (memset, adjacent)
    int* rowptr    = (int*)(mb + W + 32);                  // n2
    int* ex        = rowptr + n2;                          // n2
    int* bsum      = ex + n2;                              // 256
    int* mex       = bsum + 256;                           // W
    int* mbsum     = mex + W;                              // 32
    int* livelist  = mbsum + 32;                           // N
    int* nLive     = livelist + N;                         // 1

    int gH0  = (E0 + 1023) / 1024;
    int gH1  = (E1 + 1023) / 1024;
    int gLin = (N + 31) / 32;
    int gS   = (n2 + 255) / 256;
    int gMs  = (W + 255) / 256;

    // 1. zero cnt + maskbits (contiguous)
    hipMemsetAsync(cnt, 0, ((size_t)n2 + W + 32) * sizeof(int), stream);
    // 2. mark live nodes (bitmask)
    k_mark<<<gH1, 256, 0, stream>>>(ei1, ei1 + E1, E1, BS, mb);
    // 3. F1: linear0 || filtered hist (both convs) || mscanA
    k_histlin<<<gLin + gH0 + gH1 + gMs, 256, 0, stream>>>(
        embs, w0, b0, xl, N, gLin, gH0, gH1,
        ei0 + E0, E0, ei1 + E1, E1, BS, mb, cnt, rank, N, W, mex, mbsum);
    // 4. CSR scanA + mscanB
    k_scanA2<<<gS + 1, 256, 0, stream>>>(cnt, n2, ex, bsum, gS, mbsum, gMs);
    // 5. livelist compaction + CSR scanB
    k_mscanC2<<<gMs + 1, 256, 0, stream>>>(mb, W, mex, mbsum, livelist, nLive,
                                           gMs, bsum, gS);
    // 6. CSR scanC
    k_scanC<<<gS, 256, 0, stream>>>(ex, bsum, rowptr, n2);
    // 7. F2: fill both convs' live edges
    k_fill<<<gH0 + gH1, 256, 0, stream>>>(ei0, ei0 + E0, E0, ei1, ei1 + E1, E1,
                                          BS, gH0, mb, rowptr, rank, ssrc, N);
    // 8. agg0 over live nodes only
    k_aggL<<<(N + 3) / 4, 256, 0, stream>>>(xl, rowptr, cnt, ssrc, att0, bias0,
                                            out, livelist, nLive);
    // 9. lin1 over live rows only (gelu)
    k_linC<<<gLin, 256, 0, stream>>>(out, w1, b1, xl, livelist, nLive);
    // 10. agg1 (dst<BS) + head
    k_agg1head<<<(BS + 3) / 4, 256, 0, stream>>>(
        xl, rowptr, cnt, ssrc, att1, bias1,
        wout, bout, gamma, beta, (float*)d_out, N, BS);
}